// Round 3
// baseline (15971.223 us; speedup 1.0000x reference)
//
#include <hip/hip_runtime.h>
#include <hip/hip_cooperative_groups.h>
#include <math.h>

namespace cg = cooperative_groups;

#define BB 32
#define TT 64
#define INPW 90
#define NU 4
#define NH1 2048
#define NHC 1024
#define NHD 1024
#define NZ 512

typedef unsigned short u16;
typedef __attribute__((ext_vector_type(8))) short short8;
typedef __attribute__((ext_vector_type(4))) float f32x4;

__device__ __forceinline__ float sigf(float v) { return 1.0f / (1.0f + __expf(-v)); }

__device__ __forceinline__ u16 f2bf(float f) {
  unsigned u = __float_as_uint(f);
  unsigned r = (u + 0x7FFFu + ((u >> 16) & 1u)) >> 16;
  return (u16)r;
}
__device__ __forceinline__ float bf2f(u16 b) { return __uint_as_float(((unsigned)b) << 16); }

__device__ __forceinline__ f32x4 bmfma(uint4 a, uint4 b, f32x4 c) {
  return __builtin_amdgcn_mfma_f32_16x16x32_bf16(*(short8*)&a, *(short8*)&b, c, 0, 0, 0);
}

// ---------------- conversion kernels ----------------
__global__ void cvt_flat(const float* __restrict__ s, u16* __restrict__ d, long n) {
  long i = ((long)blockIdx.x * 256 + threadIdx.x) * 4;
  if (i >= n) return;
  float4 v = *(const float4*)&s[i];
  d[i] = f2bf(v.x); d[i + 1] = f2bf(v.y); d[i + 2] = f2bf(v.z); d[i + 3] = f2bf(v.w);
}

__global__ void cvt_pad(const float* __restrict__ s, int sld, int cols,
                        u16* __restrict__ d, int dld, int rows) {
  int c = blockIdx.x * blockDim.x + threadIdx.x;
  int r = blockIdx.y;
  if (c >= dld) return;
  d[(long)r * dld + c] = (c < cols) ? f2bf(s[(long)r * sld + c]) : (u16)0;
}

// x[b][t][90] -> xb[(t*32+b)][128] bf16 (zero-padded)
__global__ void xcvt(const float* __restrict__ x, u16* __restrict__ xb) {
  int r = blockIdx.x, c = threadIdx.x;
  int b = r & 31, t = r >> 5;
  float v = (c < INPW) ? x[((long)b * TT + t) * INPW + c] : 0.0f;
  xb[(long)r * 128 + c] = f2bf(v);
}

// w4t[k][n'] = w4[n'][k] padded to 128 cols, bf16
__global__ void w4t_k(const float* __restrict__ w4, u16* __restrict__ w4tb) {
  int k = blockIdx.x, n = threadIdx.x;
  w4tb[(long)k * 128 + n] = (n < INPW) ? f2bf(w4[(long)n * NHD + k]) : (u16)0;
}

// bfuse[r] = sum_n d1_wih[r][1024+n] * b4[n]
__global__ void bfuse_k(const float* __restrict__ d1_wih, const float* __restrict__ b4,
                        float* __restrict__ bfuse) {
  int r = blockIdx.x * 256 + threadIdx.x;
  if (r >= 4096) return;
  float s = 0.0f;
  for (int n = 0; n < INPW; ++n) s += d1_wih[(long)r * 1114 + 1024 + n] * b4[n];
  bfuse[r] = s;
}

// ---------------- bf16 MFMA GEMM: C[M][N] = A[M][K]*Bw[N][K]^T + bias, bf16 out ----------------
__global__ __launch_bounds__(256) void gemm_bf(
    const u16* __restrict__ A, int lda, const u16* __restrict__ Bw, int ldb,
    const float* __restrict__ bias, u16* __restrict__ C, int ldc, int K) {
  __shared__ u16 Asm[128 * 64];
  __shared__ u16 Bsm[128 * 64];
  const int tid = threadIdx.x;
  const int w = tid >> 6, q = (tid >> 4) & 3, ln = tid & 15;
  const int wm = w & 1, wn = w >> 1;
  const long am0 = (long)blockIdx.x * 128;
  const long bn0 = (long)blockIdx.y * 128;
  f32x4 acc[4][4] = {};
  const int srow = tid >> 3, ssl = tid & 7;
  const u16* Ap = A + (am0 + srow) * lda + ssl * 8;
  const u16* Bp = Bw + (bn0 + srow) * ldb + ssl * 8;
  uint4 va[4], vb[4];
  int soff[4];
#pragma unroll
  for (int i = 0; i < 4; ++i) {
    va[i] = *(const uint4*)(Ap + (long)i * 32 * lda);
    vb[i] = *(const uint4*)(Bp + (long)i * 32 * ldb);
    int r = srow + i * 32;
    soff[i] = r * 64 + ((ssl ^ (r & 7)) << 3);
  }
  int k0 = 0;
  for (;;) {
    __syncthreads();
#pragma unroll
    for (int i = 0; i < 4; ++i) {
      *(uint4*)&Asm[soff[i]] = va[i];
      *(uint4*)&Bsm[soff[i]] = vb[i];
    }
    __syncthreads();
    k0 += 64;
    if (k0 < K) {
#pragma unroll
      for (int i = 0; i < 4; ++i) {
        va[i] = *(const uint4*)(Ap + k0 + (long)i * 32 * lda);
        vb[i] = *(const uint4*)(Bp + k0 + (long)i * 32 * ldb);
      }
    }
#pragma unroll
    for (int kh = 0; kh < 2; ++kh) {
      short8 af[4], bg[4];
#pragma unroll
      for (int t = 0; t < 4; ++t) {
        int arr = wm * 64 + t * 16 + ln;
        af[t] = *(short8*)&Asm[arr * 64 + (((q + 4 * kh) ^ (arr & 7)) << 3)];
        int brr = wn * 64 + t * 16 + ln;
        bg[t] = *(short8*)&Bsm[brr * 64 + (((q + 4 * kh) ^ (brr & 7)) << 3)];
      }
#pragma unroll
      for (int mt = 0; mt < 4; ++mt)
#pragma unroll
        for (int nt = 0; nt < 4; ++nt)
          acc[mt][nt] = __builtin_amdgcn_mfma_f32_16x16x32_bf16(af[mt], bg[nt], acc[mt][nt], 0, 0, 0);
    }
    if (k0 >= K) break;
  }
#pragma unroll
  for (int nt = 0; nt < 4; ++nt) {
    long n = bn0 + wn * 64 + nt * 16 + ln;
    float bv = bias ? bias[n] : 0.0f;
#pragma unroll
    for (int mt = 0; mt < 4; ++mt) {
#pragma unroll
      for (int r = 0; r < 4; ++r) {
        long m = am0 + wm * 64 + mt * 16 + (q << 2) + r;
        C[m * ldc + n] = f2bf(acc[mt][nt][r] + bv);
      }
    }
  }
}

// ---------------- fp32 GEMM for latent path ----------------
__global__ __launch_bounds__(256) void gemm128(
    const float* __restrict__ A, int lda, const float* __restrict__ W, int ldw,
    const float* __restrict__ bias, float* __restrict__ C, int ldc,
    int M, int K, int act, u16* __restrict__ Cb) {
  __shared__ float As[16][132];
  __shared__ float Bs[16][132];
  const int tid = threadIdx.x;
  const int bm = blockIdx.x, bn = blockIdx.y;
  const int tm = tid & 15, tn = tid >> 4;
  float acc[8][8] = {};
  for (int k0 = 0; k0 < K; k0 += 16) {
#pragma unroll
    for (int it = 0; it < 2; ++it) {
      int e = it * 256 + tid;
      int r = e >> 2, c4 = (e & 3) * 4;
      int m = bm * 128 + r;
      float4 v = make_float4(0.f, 0.f, 0.f, 0.f);
      if (m < M) v = *(const float4*)&A[(long)m * lda + k0 + c4];
      As[c4 + 0][r] = v.x; As[c4 + 1][r] = v.y; As[c4 + 2][r] = v.z; As[c4 + 3][r] = v.w;
      int n = bn * 128 + r;
      float4 w = *(const float4*)&W[(long)n * ldw + k0 + c4];
      Bs[c4 + 0][r] = w.x; Bs[c4 + 1][r] = w.y; Bs[c4 + 2][r] = w.z; Bs[c4 + 3][r] = w.w;
    }
    __syncthreads();
#pragma unroll
    for (int kk = 0; kk < 16; ++kk) {
      float4 a0 = *(const float4*)&As[kk][tm * 8];
      float4 a1 = *(const float4*)&As[kk][tm * 8 + 4];
      float4 b0 = *(const float4*)&Bs[kk][tn * 8];
      float4 b1 = *(const float4*)&Bs[kk][tn * 8 + 4];
      float av[8] = {a0.x, a0.y, a0.z, a0.w, a1.x, a1.y, a1.z, a1.w};
      float bv[8] = {b0.x, b0.y, b0.z, b0.w, b1.x, b1.y, b1.z, b1.w};
#pragma unroll
      for (int i = 0; i < 8; ++i)
#pragma unroll
        for (int j = 0; j < 8; ++j)
          acc[i][j] += av[i] * bv[j];
    }
    __syncthreads();
  }
#pragma unroll
  for (int i = 0; i < 8; ++i) {
    int m = bm * 128 + tm * 8 + i;
    if (m >= M) continue;
#pragma unroll
    for (int j = 0; j < 8; ++j) {
      int n = bn * 128 + tn * 8 + j;
      float v = acc[i][j] + bias[n];
      if (act == 1) v = tanhf(v);
      else if (act == 2) v = log1pf(__expf(v));
      C[(long)m * ldc + n] = v;
      if (Cb) Cb[(long)m * ldc + n] = f2bf(v);
    }
  }
}

__global__ void zcalc_kernel(const float* __restrict__ zm, const float* __restrict__ zs,
                             const float* __restrict__ eps, float* __restrict__ z) {
  int e = blockIdx.x * 256 + threadIdx.x;
  if (e < BB * NZ) z[e] = zm[e] + eps[e] * zs[e];
}

__global__ void softmax_kernel(float* __restrict__ out) {
  long row = blockIdx.x;
  float* p = out + row * INPW;
  int lane = threadIdx.x;
  float v0 = (lane < INPW) ? p[lane] : -1e30f;
  float v1 = (lane + 64 < INPW) ? p[lane + 64] : -1e30f;
  float m = fmaxf(v0, v1);
#pragma unroll
  for (int off = 32; off > 0; off >>= 1) m = fmaxf(m, __shfl_xor(m, off));
  float e0 = (lane < INPW) ? __expf(v0 - m) : 0.0f;
  float e1 = (lane + 64 < INPW) ? __expf(v1 - m) : 0.0f;
  float sum = e0 + e1;
#pragma unroll
  for (int off = 32; off > 0; off >>= 1) sum += __shfl_xor(sum, off);
  float inv = 1.0f / sum;
  if (lane < INPW) p[lane] = e0 * inv;
  if (lane + 64 < INPW) p[lane + 64] = e1 * inv;
}

// ---------------- cooperative encoder (one bi-dir LSTM layer, 64 steps) ----------------
// 256 blocks x 256 thr. dir = blk>>7, j0 = (blk&127)*16. 4 waves, wave w owns 4 hiddens.
// MFMA fragments loaded straight from global: A lane l: row l&15, k=(l>>4)*8 (16B);
// B lane l: batch l&15, k=(l>>4)*8 (16B).
struct EncArgs {
  const u16* whh[2];
  const u16* xp[2];     // [64*32][8192] precomputed x-proj incl bih
  const float* bhh[2];
  float* cst[2];        // [32][2048]
  u16* y0b;             // layer0 out [64*32][4096]
  u16* hpp[2];          // layer1 ping-pong [2][32][2048]
  float* htb;           // layer1 final fp32 [32][4096]
  int layer;
};

__global__ __launch_bounds__(256, 1) void enc_coop(EncArgs A) {
  cg::grid_group grid = cg::this_grid();
  const int bidx = blockIdx.x;
  const int dir = bidx >> 7;
  const int j0 = (bidx & 127) << 4;
  const int tid = threadIdx.x;
  const int w = tid >> 6, l = tid & 63;
  const int t = l & 15, kg = l >> 4;
  const long grow = (long)(t & 3) * 2048 + (j0 + 4 * w + (t >> 2));
  const u16* Wrow = A.whh[dir] + grow * 2048 + kg * 8;
  const int jout = j0 + 4 * w + kg;
  const int b0 = l & 15;
  const float* bhh = A.bhh[dir];
  float* cst = A.cst[dir];
  const u16* xp = A.xp[dir];
  const float bi0 = bhh[jout], bi1 = bhh[2048 + jout],
              bi2 = bhh[4096 + jout], bi3 = bhh[6144 + jout];

  for (int s = 0; s < 64; ++s) {
    if (s) grid.sync();
    const int tt = dir ? 63 - s : s;
    f32x4 acc0 = {0.f, 0.f, 0.f, 0.f}, acc1 = {0.f, 0.f, 0.f, 0.f};
    if (s) {
      const u16* hb; long hld;
      if (A.layer == 0) {
        int tp = dir ? tt + 1 : tt - 1;
        hb = A.y0b + (long)tp * 32 * 4096 + dir * 2048;
        hld = 4096;
      } else {
        hb = A.hpp[dir] + (long)((s - 1) & 1) * 32 * 2048;
        hld = 2048;
      }
      const u16* x0 = hb + (long)b0 * hld + kg * 8;
      const u16* x1 = hb + (long)(b0 + 16) * hld + kg * 8;
      const u16* wp = Wrow;
      for (int ks = 0; ks < 64; ks += 8) {
        uint4 av[8], bv0[8], bv1[8];
#pragma unroll
        for (int uu = 0; uu < 8; ++uu) {
          av[uu]  = *(const uint4*)(wp + (long)(ks + uu) * 32);
          bv0[uu] = *(const uint4*)(x0 + (long)(ks + uu) * 32);
          bv1[uu] = *(const uint4*)(x1 + (long)(ks + uu) * 32);
        }
#pragma unroll
        for (int uu = 0; uu < 8; ++uu) {
          acc0 = bmfma(av[uu], bv0[uu], acc0);
          acc1 = bmfma(av[uu], bv1[uu], acc1);
        }
      }
    }
#pragma unroll
    for (int half = 0; half < 2; ++half) {
      f32x4 a = half ? acc1 : acc0;
      int batch = b0 + 16 * half;
      const u16* xr = xp + ((long)tt * 32 + batch) * 8192;
      float g0 = a[0] + bi0 + bf2f(xr[jout]);
      float g1 = a[1] + bi1 + bf2f(xr[2048 + jout]);
      float g2 = a[2] + bi2 + bf2f(xr[4096 + jout]);
      float g3 = a[3] + bi3 + bf2f(xr[6144 + jout]);
      float iv = sigf(g0), fv = sigf(g1), gv = tanhf(g2), ov = sigf(g3);
      float co = s ? cst[batch * 2048 + jout] : 0.0f;
      float c = fv * co + iv * gv;
      float h = ov * tanhf(c);
      cst[batch * 2048 + jout] = c;
      if (A.layer == 0) {
        A.y0b[((long)tt * 32 + batch) * 4096 + dir * 2048 + jout] = f2bf(h);
      } else {
        A.hpp[dir][(long)(s & 1) * 32 * 2048 + batch * 2048 + jout] = f2bf(h);
        if (s == 63) A.htb[batch * 4096 + dir * 2048 + jout] = h;
      }
    }
  }
}

// ---------------- H=1024 cell phase (16 gate rows per block, 256 blocks) ----------------
// waves: w&1 = batch half, w>>1 = k half; cross-wave k-reduce via LDS.
__device__ __forceinline__ void cell1024(
    int j0, int tid, float* red,
    const u16* X0, long x0ld, const u16* W0,
    const u16* X1, long x1ld, const u16* W1,
    const u16* XP, long xpld,
    const float* biasA, const float* biasB, const float* biasC,
    const float* cin, long cld, float* cout,
    u16* hout, long hld, float* houtf, long hfld) {
  const int w = tid >> 6, l = tid & 63;
  const int bh = w & 1, kh = w >> 1;
  const int t = l & 15, kg = l >> 4;
  const long grow = (long)(t & 3) * 1024 + j0 + (t >> 2);
  const int koff = kh * 512 + kg * 8;
  f32x4 acc = {0.f, 0.f, 0.f, 0.f};
  if (X0) {
    const u16* wp = W0 + grow * 1024 + koff;
    const u16* xpt = X0 + (long)(bh * 16 + (l & 15)) * x0ld + koff;
    for (int ks = 0; ks < 16; ks += 8) {
      uint4 av[8], bv[8];
#pragma unroll
      for (int uu = 0; uu < 8; ++uu) {
        av[uu] = *(const uint4*)(wp + (long)(ks + uu) * 32);
        bv[uu] = *(const uint4*)(xpt + (long)(ks + uu) * 32);
      }
#pragma unroll
      for (int uu = 0; uu < 8; ++uu) acc = bmfma(av[uu], bv[uu], acc);
    }
  }
  if (X1) {
    const u16* wp = W1 + grow * 1024 + koff;
    const u16* xpt = X1 + (long)(bh * 16 + (l & 15)) * x1ld + koff;
    for (int ks = 0; ks < 16; ks += 8) {
      uint4 av[8], bv[8];
#pragma unroll
      for (int uu = 0; uu < 8; ++uu) {
        av[uu] = *(const uint4*)(wp + (long)(ks + uu) * 32);
        bv[uu] = *(const uint4*)(xpt + (long)(ks + uu) * 32);
      }
#pragma unroll
      for (int uu = 0; uu < 8; ++uu) acc = bmfma(av[uu], bv[uu], acc);
    }
  }
  __syncthreads();
  if (kh) *(f32x4*)&red[(bh * 64 + l) * 4] = acc;
  __syncthreads();
  if (!kh) {
    f32x4 o = *(f32x4*)&red[(bh * 64 + l) * 4];
    const int jout = j0 + kg;
    const int batch = bh * 16 + (l & 15);
    float g[4];
#pragma unroll
    for (int r = 0; r < 4; ++r) {
      float gg = acc[r] + o[r] + biasA[r * 1024 + jout];
      if (biasB) gg += biasB[r * 1024 + jout];
      if (biasC) gg += biasC[r * 1024 + jout];
      if (XP) gg += bf2f(XP[(long)batch * xpld + r * 1024 + jout]);
      g[r] = gg;
    }
    float iv = sigf(g[0]), fv = sigf(g[1]), gv = tanhf(g[2]), ov = sigf(g[3]);
    float co = cin ? cin[(long)batch * cld + jout] : 0.0f;
    float c = fv * co + iv * gv;
    float h = ov * tanhf(c);
    cout[(long)batch * 1024 + jout] = c;
    hout[(long)batch * hld + jout] = f2bf(h);
    if (houtf) houtf[(long)batch * hfld + jout] = h;
  }
}

// ---------------- cooperative conductor (2-layer, 4 steps) ----------------
struct CondArgs {
  const u16 *c0h, *c1w, *c1h, *tvecb;
  const float* tvec;
  u16 *yc0b, *embb;
  float* embf;
  float *cc0, *cc1;
  const float *b0i, *b0h, *b1i, *b1h;
};
__global__ __launch_bounds__(256, 1) void cond_coop(CondArgs A) {
  cg::grid_group grid = cg::this_grid();
  __shared__ __align__(16) float red[512];
  const int j0 = blockIdx.x * 4;
  const int tid = threadIdx.x;
  for (int u = 0; u < NU; ++u) {
    // layer 0: gates = h@c0h^T + bih + bhh  (input is zero)
    cell1024(j0, tid, red,
             u ? A.yc0b + (long)(u - 1) * 32 * 1024 : A.tvecb, u ? 1024 : 4096, A.c0h,
             nullptr, 0, nullptr,
             nullptr, 0,
             A.b0i, A.b0h, nullptr,
             u ? A.cc0 : A.tvec + 2048, u ? 1024 : 4096, A.cc0,
             A.yc0b + (long)u * 32 * 1024, 1024, nullptr, 0);
    grid.sync();
    // layer 1: gates = yc0[u]@c1w^T + h@c1h^T + bih + bhh
    cell1024(j0, tid, red,
             A.yc0b + (long)u * 32 * 1024, 1024, A.c1w,
             u ? A.embb + (long)(u - 1) * 32 * 1024 : A.tvecb + 1024, u ? 1024 : 4096, A.c1h,
             nullptr, 0,
             A.b1i, A.b1h, nullptr,
             u ? A.cc1 : A.tvec + 3072, u ? 1024 : 4096, A.cc1,
             A.embb + (long)u * 32 * 1024, 1024, A.embf + (long)u * 32 * 1024, 1024);
    grid.sync();
  }
}

// ---------------- cooperative hierarchical decoder (64 steps, 2 cells each) ----------------
// cell1 gates = dh1@d1h^T + dh2_prev@Wfuse^T + xeb[u] + d1_bhh + bfuse
//   (Wfuse = d1_wih[:,1024:]@w4 folds the p-feedback; p recovered at the end from dh2 history)
struct DecArgs {
  const u16 *d1h, *wfuse, *d2w, *d2h, *xeb, *sallb;
  const float* sall;
  u16 *dh1b, *dh2all;
  float *dc1, *dc2;
  const float *bfuse, *b1h, *b2i, *b2h;
};
__global__ __launch_bounds__(256, 1) void dec_coop(DecArgs A) {
  cg::grid_group grid = cg::this_grid();
  __shared__ __align__(16) float red[512];
  const int j0 = blockIdx.x * 4;
  const int tid = threadIdx.x;
  for (int t = 0; t < TT; ++t) {
    const int u = t >> 4, sg = t & 15;
    cell1024(j0, tid, red,
             sg ? A.dh1b + (long)((t - 1) & 1) * 32 * 1024 : A.sallb + (long)u * 32 * 4096,
             sg ? 1024 : 4096, A.d1h,
             t ? A.dh2all + (long)(t - 1) * 32 * 1024 : nullptr, 1024, A.wfuse,
             A.xeb + (long)u * 32 * 4096, 4096,
             A.b1h, t ? A.bfuse : nullptr, nullptr,
             sg ? A.dc1 : A.sall + (long)u * 32 * 4096 + 2048, sg ? 1024 : 4096, A.dc1,
             A.dh1b + (long)(t & 1) * 32 * 1024, 1024, nullptr, 0);
    grid.sync();
    cell1024(j0, tid, red,
             A.dh1b + (long)(t & 1) * 32 * 1024, 1024, A.d2w,
             sg ? A.dh2all + (long)(t - 1) * 32 * 1024 : A.sallb + (long)u * 32 * 4096 + 1024,
             sg ? 1024 : 4096, A.d2h,
             nullptr, 0,
             A.b2i, A.b2h, nullptr,
             sg ? A.dc2 : A.sall + (long)u * 32 * 4096 + 3072, sg ? 1024 : 4096, A.dc2,
             A.dh2all + (long)t * 32 * 1024, 1024, nullptr, 0);
    grid.sync();
  }
}

// ---------------- final p = dh2all @ w4^T + b4 -> out (fp32, [b][t][90]) ----------------
__global__ __launch_bounds__(256) void proj_all(const u16* __restrict__ dh2all,
                                                const u16* __restrict__ w4b,
                                                const float* __restrict__ b4,
                                                float* __restrict__ out) {
  __shared__ u16 hs[8 * 1024];
  const int r0 = blockIdx.x * 8;
  for (int e = threadIdx.x; e < 1024; e += 256)
    ((uint4*)hs)[e] = ((const uint4*)(dh2all + (long)r0 * 1024))[e];
  __syncthreads();
  for (int o = threadIdx.x; o < 8 * INPW; o += 256) {
    int rr = o / INPW, n = o % INPW;
    const u16* wr = w4b + (long)n * 1024;
    const u16* hr = hs + rr * 1024;
    float s = 0.0f;
    for (int k = 0; k < 1024; ++k) s += bf2f(hr[k]) * bf2f(wr[k]);
    int row = r0 + rr;            // = t*32 + b
    int tt = row >> 5, b = row & 31;
    out[((long)b * TT + tt) * INPW + n] = s + b4[n];
  }
}

// =====================================================================
extern "C" void kernel_launch(void* const* d_in, const int* in_sizes, int n_in,
                              void* d_out, int out_size, void* d_ws, size_t ws_size,
                              hipStream_t stream) {
  (void)in_sizes; (void)n_in; (void)out_size;
  const float* x        = (const float*)d_in[0];
  const float* eps      = (const float*)d_in[1];
  const float* e0f_wih  = (const float*)d_in[2];
  const float* e0f_whh  = (const float*)d_in[3];
  const float* e0f_bih  = (const float*)d_in[4];
  const float* e0f_bhh  = (const float*)d_in[5];
  const float* e0b_wih  = (const float*)d_in[6];
  const float* e0b_whh  = (const float*)d_in[7];
  const float* e0b_bih  = (const float*)d_in[8];
  const float* e0b_bhh  = (const float*)d_in[9];
  const float* e1f_wih  = (const float*)d_in[10];
  const float* e1f_whh  = (const float*)d_in[11];
  const float* e1f_bih  = (const float*)d_in[12];
  const float* e1f_bhh  = (const float*)d_in[13];
  const float* e1b_wih  = (const float*)d_in[14];
  const float* e1b_whh  = (const float*)d_in[15];
  const float* e1b_bih  = (const float*)d_in[16];
  const float* e1b_bhh  = (const float*)d_in[17];
  const float* wm  = (const float*)d_in[18];
  const float* bm  = (const float*)d_in[19];
  const float* wsw = (const float*)d_in[20];
  const float* bsv = (const float*)d_in[21];
  const float* w2  = (const float*)d_in[22];
  const float* b2  = (const float*)d_in[23];
  const float* c0_whh = (const float*)d_in[25];
  const float* c0_bih = (const float*)d_in[26];
  const float* c0_bhh = (const float*)d_in[27];
  const float* c1_wih = (const float*)d_in[28];
  const float* c1_whh = (const float*)d_in[29];
  const float* c1_bih = (const float*)d_in[30];
  const float* c1_bhh = (const float*)d_in[31];
  const float* w3 = (const float*)d_in[32];
  const float* b3 = (const float*)d_in[33];
  const float* d1_wih = (const float*)d_in[34];
  const float* d1_whh = (const float*)d_in[35];
  const float* d1_bih = (const float*)d_in[36];
  const float* d1_bhh = (const float*)d_in[37];
  const float* d2_wih = (const float*)d_in[38];
  const float* d2_whh = (const float*)d_in[39];
  const float* d2_bih = (const float*)d_in[40];
  const float* d2_bhh = (const float*)d_in[41];
  const float* w4 = (const float*)d_in[42];
  const float* b4 = (const float*)d_in[43];

  float* out = (float*)d_out;
  float* zm_out = out + (size_t)BB * TT * INPW;
  float* zs_out = zm_out + BB * NZ;

  char* wbase = (char*)d_ws;
  size_t cur = 0;
  auto AL = [&](size_t bytes) -> void* {
    void* p = wbase + cur;
    cur = (cur + bytes + 255) & ~(size_t)255;
    return p;
  };
  u16* xb    = (u16*)AL(2048L * 128 * 2);
  u16* e0wf  = (u16*)AL(8192L * 128 * 2);
  u16* e0wb  = (u16*)AL(8192L * 128 * 2);
  u16* e0hf  = (u16*)AL(8192L * 2048 * 2);
  u16* e0hb  = (u16*)AL(8192L * 2048 * 2);
  u16* e1wf  = (u16*)AL(8192L * 4096 * 2);
  u16* e1wb  = (u16*)AL(8192L * 4096 * 2);
  u16* e1hf  = (u16*)AL(8192L * 2048 * 2);
  u16* e1hb  = (u16*)AL(8192L * 2048 * 2);
  u16* c0h   = (u16*)AL(4096L * 1024 * 2);
  u16* c1w   = (u16*)AL(4096L * 1024 * 2);
  u16* c1h   = (u16*)AL(4096L * 1024 * 2);
  u16* d1we  = (u16*)AL(4096L * 1024 * 2);
  u16* d1wp  = (u16*)AL(4096L * 128 * 2);
  u16* d1h   = (u16*)AL(4096L * 1024 * 2);
  u16* d2w   = (u16*)AL(4096L * 1024 * 2);
  u16* d2h   = (u16*)AL(4096L * 1024 * 2);
  u16* w4b   = (u16*)AL(90L * 1024 * 2);
  u16* w4tb  = (u16*)AL(1024L * 128 * 2);
  u16* wfuse = (u16*)AL(4096L * 1024 * 2);
  float* bfuse = (float*)AL(4096L * 4);
  u16* xp0f  = (u16*)AL(2048L * 8192 * 2);
  u16* xp0b  = (u16*)AL(2048L * 8192 * 2);
  u16* y0b   = (u16*)AL(2048L * 4096 * 2);
  u16* xp1f  = (u16*)AL(2048L * 8192 * 2);
  u16* xp1b  = (u16*)AL(2048L * 8192 * 2);
  u16* hppf  = (u16*)AL(2L * 32 * 2048 * 2);
  u16* hppb  = (u16*)AL(2L * 32 * 2048 * 2);
  u16* tvecb = (u16*)AL(32L * 4096 * 2);
  u16* yc0b  = (u16*)AL(4L * 32 * 1024 * 2);
  u16* embb  = (u16*)AL(4L * 32 * 1024 * 2);
  u16* sallb = (u16*)AL(128L * 4096 * 2);
  u16* xeb   = (u16*)AL(128L * 4096 * 2);
  u16* dh1b  = (u16*)AL(2L * 32 * 1024 * 2);
  u16* dh2all= (u16*)AL(64L * 32 * 1024 * 2);
  float* c0f_ = (float*)AL(32L * 2048 * 4);
  float* c0b_ = (float*)AL(32L * 2048 * 4);
  float* c1f_ = (float*)AL(32L * 2048 * 4);
  float* c1b_ = (float*)AL(32L * 2048 * 4);
  float* htb  = (float*)AL(32L * 4096 * 4);
  float* zbuf = (float*)AL(32L * 512 * 4);
  float* tvec = (float*)AL(32L * 4096 * 4);
  float* cc0  = (float*)AL(32L * 1024 * 4);
  float* cc1  = (float*)AL(32L * 1024 * 4);
  float* embf = (float*)AL(128L * 1024 * 4);
  float* sall = (float*)AL(128L * 4096 * 4);
  float* dc1  = (float*)AL(32L * 1024 * 4);
  float* dc2  = (float*)AL(32L * 1024 * 4);
  if (cur > ws_size) return;

  // ---- conversions ----
  auto cf = [&](const float* s, u16* d, long n) {
    cvt_flat<<<dim3((unsigned)((n / 4 + 255) / 256)), 256, 0, stream>>>(s, d, n);
  };
  cf(e0f_whh, e0hf, 8192L * 2048);
  cf(e0b_whh, e0hb, 8192L * 2048);
  cf(e1f_wih, e1wf, 8192L * 4096);
  cf(e1b_wih, e1wb, 8192L * 4096);
  cf(e1f_whh, e1hf, 8192L * 2048);
  cf(e1b_whh, e1hb, 8192L * 2048);
  cf(c0_whh, c0h, 4096L * 1024);
  cf(c1_wih, c1w, 4096L * 1024);
  cf(c1_whh, c1h, 4096L * 1024);
  cf(d1_whh, d1h, 4096L * 1024);
  cf(d2_wih, d2w, 4096L * 1024);
  cf(d2_whh, d2h, 4096L * 1024);
  cf(w4, w4b, 90L * 1024);
  cvt_pad<<<dim3(1, 8192), 128, 0, stream>>>(e0f_wih, 90, 90, e0wf, 128, 8192);
  cvt_pad<<<dim3(1, 8192), 128, 0, stream>>>(e0b_wih, 90, 90, e0wb, 128, 8192);
  cvt_pad<<<dim3(4, 4096), 256, 0, stream>>>(d1_wih, 1114, 1024, d1we, 1024, 4096);
  cvt_pad<<<dim3(1, 4096), 128, 0, stream>>>(d1_wih + 1024, 1114, 90, d1wp, 128, 4096);
  xcvt<<<dim3(2048), 128, 0, stream>>>(x, xb);
  w4t_k<<<dim3(1024), 128, 0, stream>>>(w4, w4tb);
  bfuse_k<<<dim3(16), 256, 0, stream>>>(d1_wih, b4, bfuse);

  // Wfuse = d1wp(4096x128) @ w4t(1024x128)^T
  gemm_bf<<<dim3(32, 8), 256, 0, stream>>>(d1wp, 128, w4tb, 128, nullptr, wfuse, 1024, 128);

  // ---- layer-0 input projections ----
  gemm_bf<<<dim3(16, 64), 256, 0, stream>>>(xb, 128, e0wf, 128, e0f_bih, xp0f, 8192, 128);
  gemm_bf<<<dim3(16, 64), 256, 0, stream>>>(xb, 128, e0wb, 128, e0b_bih, xp0b, 8192, 128);

  // ---- encoder layer 0 (cooperative) ----
  {
    EncArgs ea{};
    ea.whh[0] = e0hf; ea.whh[1] = e0hb;
    ea.xp[0] = xp0f; ea.xp[1] = xp0b;
    ea.bhh[0] = e0f_bhh; ea.bhh[1] = e0b_bhh;
    ea.cst[0] = c0f_; ea.cst[1] = c0b_;
    ea.y0b = y0b; ea.hpp[0] = hppf; ea.hpp[1] = hppb; ea.htb = htb; ea.layer = 0;
    void* args[] = {&ea};
    hipLaunchCooperativeKernel((void*)enc_coop, dim3(256), dim3(256), args, 0, stream);
  }

  // ---- layer-1 input projections ----
  gemm_bf<<<dim3(16, 64), 256, 0, stream>>>(y0b, 4096, e1wf, 4096, e1f_bih, xp1f, 8192, 4096);
  gemm_bf<<<dim3(16, 64), 256, 0, stream>>>(y0b, 4096, e1wb, 4096, e1b_bih, xp1b, 8192, 4096);

  // ---- encoder layer 1 (cooperative) ----
  {
    EncArgs ea{};
    ea.whh[0] = e1hf; ea.whh[1] = e1hb;
    ea.xp[0] = xp1f; ea.xp[1] = xp1b;
    ea.bhh[0] = e1f_bhh; ea.bhh[1] = e1b_bhh;
    ea.cst[0] = c1f_; ea.cst[1] = c1b_;
    ea.y0b = y0b; ea.hpp[0] = hppf; ea.hpp[1] = hppb; ea.htb = htb; ea.layer = 1;
    void* args[] = {&ea};
    hipLaunchCooperativeKernel((void*)enc_coop, dim3(256), dim3(256), args, 0, stream);
  }

  // ---- latent ----
  gemm128<<<dim3(1, 4), 256, 0, stream>>>(htb, 4096, wm, 4096, bm, zm_out, 512, 32, 4096, 0, nullptr);
  gemm128<<<dim3(1, 4), 256, 0, stream>>>(htb, 4096, wsw, 4096, bsv, zs_out, 512, 32, 4096, 2, nullptr);
  zcalc_kernel<<<dim3(64), 256, 0, stream>>>(zm_out, zs_out, eps, zbuf);
  gemm128<<<dim3(1, 32), 256, 0, stream>>>(zbuf, 512, w2, 512, b2, tvec, 4096, 32, 512, 1, tvecb);

  // ---- conductor (cooperative) ----
  {
    CondArgs ca{};
    ca.c0h = c0h; ca.c1w = c1w; ca.c1h = c1h;
    ca.tvecb = tvecb; ca.tvec = tvec;
    ca.yc0b = yc0b; ca.embb = embb; ca.embf = embf;
    ca.cc0 = cc0; ca.cc1 = cc1;
    ca.b0i = c0_bih; ca.b0h = c0_bhh; ca.b1i = c1_bih; ca.b1h = c1_bhh;
    void* args[] = {&ca};
    hipLaunchCooperativeKernel((void*)cond_coop, dim3(256), dim3(256), args, 0, stream);
  }

  // ---- decoder prep ----
  gemm128<<<dim3(1, 32), 256, 0, stream>>>(embf, 1024, w3, 1024, b3, sall, 4096, 128, 1024, 1, sallb);
  gemm_bf<<<dim3(1, 32), 256, 0, stream>>>(embb, 1024, d1we, 1024, d1_bih, xeb, 4096, 1024);

  // ---- hierarchical decoder (cooperative) ----
  {
    DecArgs da{};
    da.d1h = d1h; da.wfuse = wfuse; da.d2w = d2w; da.d2h = d2h;
    da.xeb = xeb; da.sallb = sallb; da.sall = sall;
    da.dh1b = dh1b; da.dh2all = dh2all;
    da.dc1 = dc1; da.dc2 = dc2;
    da.bfuse = bfuse; da.b1h = d1_bhh; da.b2i = d2_bih; da.b2h = d2_bhh;
    void* args[] = {&da};
    hipLaunchCooperativeKernel((void*)dec_coop, dim3(256), dim3(256), args, 0, stream);
  }

  // ---- outputs ----
  proj_all<<<dim3(256), 256, 0, stream>>>(dh2all, w4b, b4, out);
  softmax_kernel<<<dim3(BB * TT), 64, 0, stream>>>(out);
}

// Round 4
// 8610.934 us; speedup vs baseline: 1.8548x; 1.8548x over previous
//
#include <hip/hip_runtime.h>
#include <hip/hip_cooperative_groups.h>
#include <math.h>

#define BB 32
#define TT 64
#define INPW 90
#define NU 4
#define NH1 2048
#define NHC 1024
#define NHD 1024
#define NZ 512
#define BSTRIDE 160  // u32 per barrier slot (8 subs @ stride 16 + master @ 128)

typedef unsigned short u16;
typedef __attribute__((ext_vector_type(8))) short short8;
typedef __attribute__((ext_vector_type(4))) float f32x4;

__device__ __forceinline__ float sigf(float v) { return 1.0f / (1.0f + __expf(-v)); }

__device__ __forceinline__ u16 f2bf(float f) {
  unsigned u = __float_as_uint(f);
  unsigned r = (u + 0x7FFFu + ((u >> 16) & 1u)) >> 16;
  return (u16)r;
}
__device__ __forceinline__ float bf2f(u16 b) { return __uint_as_float(((unsigned)b) << 16); }

__device__ __forceinline__ f32x4 bmfma(uint4 a, uint4 b, f32x4 c) {
  return __builtin_amdgcn_mfma_f32_16x16x32_bf16(*(short8*)&a, *(short8*)&b, c, 0, 0, 0);
}

// ---- coherence helpers (cross-XCD, no cache flush) ----
// write-through store of one bf16 value (visible at L3 after vmcnt(0))
__device__ __forceinline__ void cstore2(u16* p, u16 v) {
  unsigned vv = v;
  asm volatile("global_store_short %0, %1, off sc0 sc1" :: "v"(p), "v"(vv) : "memory");
}
// L2-bypassing flag load
__device__ __forceinline__ unsigned fload(const unsigned* p) {
  unsigned r;
  asm volatile("global_load_dword %0, %1, off sc0 sc1\n\ts_waitcnt vmcnt(0)"
               : "=v"(r) : "v"(p) : "memory");
  return r;
}
// two-level grid barrier, one-shot per slot. base: u32[BSTRIDE]. subTarget = nblk/8.
__device__ __forceinline__ void gbar(unsigned* base, unsigned subTarget) {
  asm volatile("s_waitcnt vmcnt(0)" ::: "memory");  // drain this thread's coherent stores
  __syncthreads();
  if (threadIdx.x == 0) {
    unsigned old = atomicAdd(&base[(blockIdx.x & 7) << 4], 1u);
    if (old == subTarget - 1) atomicAdd(&base[128], 1u);
    while (fload(&base[128]) < 8u) __builtin_amdgcn_s_sleep(2);
  }
  __syncthreads();
}

// ---------------- conversion kernels ----------------
__global__ void cvt_flat(const float* __restrict__ s, u16* __restrict__ d, long n) {
  long i = ((long)blockIdx.x * 256 + threadIdx.x) * 4;
  if (i >= n) return;
  float4 v = *(const float4*)&s[i];
  d[i] = f2bf(v.x); d[i + 1] = f2bf(v.y); d[i + 2] = f2bf(v.z); d[i + 3] = f2bf(v.w);
}

__global__ void cvt_pad(const float* __restrict__ s, int sld, int cols,
                        u16* __restrict__ d, int dld, int rows) {
  int c = blockIdx.x * blockDim.x + threadIdx.x;
  int r = blockIdx.y;
  if (c >= dld) return;
  d[(long)r * dld + c] = (c < cols) ? f2bf(s[(long)r * sld + c]) : (u16)0;
}

__global__ void xcvt(const float* __restrict__ x, u16* __restrict__ xb) {
  int r = blockIdx.x, c = threadIdx.x;
  int b = r & 31, t = r >> 5;
  float v = (c < INPW) ? x[((long)b * TT + t) * INPW + c] : 0.0f;
  xb[(long)r * 128 + c] = f2bf(v);
}

__global__ void w4t_k(const float* __restrict__ w4, u16* __restrict__ w4tb) {
  int k = blockIdx.x, n = threadIdx.x;
  w4tb[(long)k * 128 + n] = (n < INPW) ? f2bf(w4[(long)n * NHD + k]) : (u16)0;
}

__global__ void bfuse_k(const float* __restrict__ d1_wih, const float* __restrict__ b4,
                        float* __restrict__ bfuse) {
  int r = blockIdx.x * 256 + threadIdx.x;
  if (r >= 4096) return;
  float s = 0.0f;
  for (int n = 0; n < INPW; ++n) s += d1_wih[(long)r * 1114 + 1024 + n] * b4[n];
  bfuse[r] = s;
}

// ---------------- bf16 MFMA GEMM ----------------
__global__ __launch_bounds__(256) void gemm_bf(
    const u16* __restrict__ A, int lda, const u16* __restrict__ Bw, int ldb,
    const float* __restrict__ bias, u16* __restrict__ C, int ldc, int K) {
  __shared__ u16 Asm[128 * 64];
  __shared__ u16 Bsm[128 * 64];
  const int tid = threadIdx.x;
  const int w = tid >> 6, q = (tid >> 4) & 3, ln = tid & 15;
  const int wm = w & 1, wn = w >> 1;
  const long am0 = (long)blockIdx.x * 128;
  const long bn0 = (long)blockIdx.y * 128;
  f32x4 acc[4][4] = {};
  const int srow = tid >> 3, ssl = tid & 7;
  const u16* Ap = A + (am0 + srow) * lda + ssl * 8;
  const u16* Bp = Bw + (bn0 + srow) * ldb + ssl * 8;
  uint4 va[4], vb[4];
  int soff[4];
#pragma unroll
  for (int i = 0; i < 4; ++i) {
    va[i] = *(const uint4*)(Ap + (long)i * 32 * lda);
    vb[i] = *(const uint4*)(Bp + (long)i * 32 * ldb);
    int r = srow + i * 32;
    soff[i] = r * 64 + ((ssl ^ (r & 7)) << 3);
  }
  int k0 = 0;
  for (;;) {
    __syncthreads();
#pragma unroll
    for (int i = 0; i < 4; ++i) {
      *(uint4*)&Asm[soff[i]] = va[i];
      *(uint4*)&Bsm[soff[i]] = vb[i];
    }
    __syncthreads();
    k0 += 64;
    if (k0 < K) {
#pragma unroll
      for (int i = 0; i < 4; ++i) {
        va[i] = *(const uint4*)(Ap + k0 + (long)i * 32 * lda);
        vb[i] = *(const uint4*)(Bp + k0 + (long)i * 32 * ldb);
      }
    }
#pragma unroll
    for (int kh = 0; kh < 2; ++kh) {
      short8 af[4], bg[4];
#pragma unroll
      for (int t = 0; t < 4; ++t) {
        int arr = wm * 64 + t * 16 + ln;
        af[t] = *(short8*)&Asm[arr * 64 + (((q + 4 * kh) ^ (arr & 7)) << 3)];
        int brr = wn * 64 + t * 16 + ln;
        bg[t] = *(short8*)&Bsm[brr * 64 + (((q + 4 * kh) ^ (brr & 7)) << 3)];
      }
#pragma unroll
      for (int mt = 0; mt < 4; ++mt)
#pragma unroll
        for (int nt = 0; nt < 4; ++nt)
          acc[mt][nt] = __builtin_amdgcn_mfma_f32_16x16x32_bf16(af[mt], bg[nt], acc[mt][nt], 0, 0, 0);
    }
    if (k0 >= K) break;
  }
#pragma unroll
  for (int nt = 0; nt < 4; ++nt) {
    long n = bn0 + wn * 64 + nt * 16 + ln;
    float bv = bias ? bias[n] : 0.0f;
#pragma unroll
    for (int mt = 0; mt < 4; ++mt) {
#pragma unroll
      for (int r = 0; r < 4; ++r) {
        long m = am0 + wm * 64 + mt * 16 + (q << 2) + r;
        C[m * ldc + n] = f2bf(acc[mt][nt][r] + bv);
      }
    }
  }
}

// ---------------- fp32 GEMM for latent path ----------------
__global__ __launch_bounds__(256) void gemm128(
    const float* __restrict__ A, int lda, const float* __restrict__ W, int ldw,
    const float* __restrict__ bias, float* __restrict__ C, int ldc,
    int M, int K, int act, u16* __restrict__ Cb) {
  __shared__ float As[16][132];
  __shared__ float Bs[16][132];
  const int tid = threadIdx.x;
  const int bm = blockIdx.x, bn = blockIdx.y;
  const int tm = tid & 15, tn = tid >> 4;
  float acc[8][8] = {};
  for (int k0 = 0; k0 < K; k0 += 16) {
#pragma unroll
    for (int it = 0; it < 2; ++it) {
      int e = it * 256 + tid;
      int r = e >> 2, c4 = (e & 3) * 4;
      int m = bm * 128 + r;
      float4 v = make_float4(0.f, 0.f, 0.f, 0.f);
      if (m < M) v = *(const float4*)&A[(long)m * lda + k0 + c4];
      As[c4 + 0][r] = v.x; As[c4 + 1][r] = v.y; As[c4 + 2][r] = v.z; As[c4 + 3][r] = v.w;
      int n = bn * 128 + r;
      float4 w = *(const float4*)&W[(long)n * ldw + k0 + c4];
      Bs[c4 + 0][r] = w.x; Bs[c4 + 1][r] = w.y; Bs[c4 + 2][r] = w.z; Bs[c4 + 3][r] = w.w;
    }
    __syncthreads();
#pragma unroll
    for (int kk = 0; kk < 16; ++kk) {
      float4 a0 = *(const float4*)&As[kk][tm * 8];
      float4 a1 = *(const float4*)&As[kk][tm * 8 + 4];
      float4 b0 = *(const float4*)&Bs[kk][tn * 8];
      float4 b1 = *(const float4*)&Bs[kk][tn * 8 + 4];
      float av[8] = {a0.x, a0.y, a0.z, a0.w, a1.x, a1.y, a1.z, a1.w};
      float bv[8] = {b0.x, b0.y, b0.z, b0.w, b1.x, b1.y, b1.z, b1.w};
#pragma unroll
      for (int i = 0; i < 8; ++i)
#pragma unroll
        for (int j = 0; j < 8; ++j)
          acc[i][j] += av[i] * bv[j];
    }
    __syncthreads();
  }
#pragma unroll
  for (int i = 0; i < 8; ++i) {
    int m = bm * 128 + tm * 8 + i;
    if (m >= M) continue;
#pragma unroll
    for (int j = 0; j < 8; ++j) {
      int n = bn * 128 + tn * 8 + j;
      float v = acc[i][j] + bias[n];
      if (act == 1) v = tanhf(v);
      else if (act == 2) v = log1pf(__expf(v));
      C[(long)m * ldc + n] = v;
      if (Cb) Cb[(long)m * ldc + n] = f2bf(v);
    }
  }
}

__global__ void zcalc_kernel(const float* __restrict__ zm, const float* __restrict__ zs,
                             const float* __restrict__ eps, float* __restrict__ z) {
  int e = blockIdx.x * 256 + threadIdx.x;
  if (e < BB * NZ) z[e] = zm[e] + eps[e] * zs[e];
}

__global__ void softmax_kernel(float* __restrict__ out) {
  long row = blockIdx.x;
  float* p = out + row * INPW;
  int lane = threadIdx.x;
  float v0 = (lane < INPW) ? p[lane] : -1e30f;
  float v1 = (lane + 64 < INPW) ? p[lane + 64] : -1e30f;
  float m = fmaxf(v0, v1);
#pragma unroll
  for (int off = 32; off > 0; off >>= 1) m = fmaxf(m, __shfl_xor(m, off));
  float e0 = (lane < INPW) ? __expf(v0 - m) : 0.0f;
  float e1 = (lane + 64 < INPW) ? __expf(v1 - m) : 0.0f;
  float sum = e0 + e1;
#pragma unroll
  for (int off = 32; off > 0; off >>= 1) sum += __shfl_xor(sum, off);
  float inv = 1.0f / sum;
  if (lane < INPW) p[lane] = e0 * inv;
  if (lane + 64 < INPW) p[lane + 64] = e1 * inv;
}

// ---------------- persistent encoder (one bi-dir LSTM layer, 64 steps) ----------------
struct EncArgs {
  const u16* whh[2];
  const u16* xp[2];
  const float* bhh[2];
  float* cst[2];
  u16* y0b;          // layer0 out / layer1 in: [64*32][4096], rolling by t
  u16* h1a[2];       // layer1 rolling h history: [64][32][2048] per dir
  float* htb;
  unsigned* bar;     // region: (dir*64 + step-1)*BSTRIDE
  int layer;
};

__global__ __launch_bounds__(256) void enc_coop(EncArgs A) {
  const int bidx = blockIdx.x;
  const int dir = bidx >> 7;
  const int j0 = (bidx & 127) << 4;
  const int tid = threadIdx.x;
  const int w = tid >> 6, l = tid & 63;
  const int tr = l & 15, kg = l >> 4;
  const long grow = (long)(tr & 3) * 2048 + (j0 + 4 * w + (tr >> 2));
  const u16* Wrow = A.whh[dir] + grow * 2048 + kg * 8;
  const int jout = j0 + 4 * w + kg;
  const int b0 = l & 15;
  const float* bhh = A.bhh[dir];
  float* cst = A.cst[dir];
  const u16* xp = A.xp[dir];
  const float bi0 = bhh[jout], bi1 = bhh[2048 + jout],
              bi2 = bhh[4096 + jout], bi3 = bhh[6144 + jout];

  for (int s = 0; s < 64; ++s) {
    if (s) gbar(A.bar + (long)(dir * 64 + (s - 1)) * BSTRIDE, 16);
    const int tt = dir ? 63 - s : s;
    f32x4 acc0 = {0.f, 0.f, 0.f, 0.f}, acc1 = {0.f, 0.f, 0.f, 0.f};
    if (s) {
      const u16* hb; long hld;
      if (A.layer == 0) {
        int tp = dir ? tt + 1 : tt - 1;
        hb = A.y0b + (long)tp * 32 * 4096 + dir * 2048;
        hld = 4096;
      } else {
        hb = A.h1a[dir] + (long)(s - 1) * 32 * 2048;
        hld = 2048;
      }
      const u16* x0 = hb + (long)b0 * hld + kg * 8;
      const u16* x1 = hb + (long)(b0 + 16) * hld + kg * 8;
      const u16* wp = Wrow;
      for (int ks = 0; ks < 64; ks += 8) {
        uint4 av[8], bv0[8], bv1[8];
#pragma unroll
        for (int uu = 0; uu < 8; ++uu) {
          av[uu]  = *(const uint4*)(wp + (long)(ks + uu) * 32);
          bv0[uu] = *(const uint4*)(x0 + (long)(ks + uu) * 32);
          bv1[uu] = *(const uint4*)(x1 + (long)(ks + uu) * 32);
        }
#pragma unroll
        for (int uu = 0; uu < 8; ++uu) {
          acc0 = bmfma(av[uu], bv0[uu], acc0);
          acc1 = bmfma(av[uu], bv1[uu], acc1);
        }
      }
    }
#pragma unroll
    for (int half = 0; half < 2; ++half) {
      f32x4 a = half ? acc1 : acc0;
      int batch = b0 + 16 * half;
      const u16* xr = xp + ((long)tt * 32 + batch) * 8192;
      float g0 = a[0] + bi0 + bf2f(xr[jout]);
      float g1 = a[1] + bi1 + bf2f(xr[2048 + jout]);
      float g2 = a[2] + bi2 + bf2f(xr[4096 + jout]);
      float g3 = a[3] + bi3 + bf2f(xr[6144 + jout]);
      float iv = sigf(g0), fv = sigf(g1), gv = tanhf(g2), ov = sigf(g3);
      float co = s ? cst[batch * 2048 + jout] : 0.0f;
      float c = fv * co + iv * gv;
      float h = ov * tanhf(c);
      cst[batch * 2048 + jout] = c;
      if (A.layer == 0) {
        cstore2(&A.y0b[((long)tt * 32 + batch) * 4096 + dir * 2048 + jout], f2bf(h));
      } else {
        cstore2(&A.h1a[dir][((long)s * 32 + batch) * 2048 + jout], f2bf(h));
        if (s == 63) A.htb[batch * 4096 + dir * 2048 + jout] = h;
      }
    }
  }
}

// ---------------- H=1024 cell phase ----------------
__device__ __forceinline__ void cell1024(
    int j0, int tid, float* red,
    const u16* X0, long x0ld, const u16* W0,
    const u16* X1, long x1ld, const u16* W1,
    const u16* XP, long xpld,
    const float* biasA, const float* biasB, const float* biasC,
    const float* cin, long cld, float* cout,
    u16* hout, long hld, float* houtf, long hfld) {
  const int w = tid >> 6, l = tid & 63;
  const int bh = w & 1, kh = w >> 1;
  const int tr = l & 15, kg = l >> 4;
  const long grow = (long)(tr & 3) * 1024 + j0 + (tr >> 2);
  const int koff = kh * 512 + kg * 8;
  f32x4 acc = {0.f, 0.f, 0.f, 0.f};
  if (X0) {
    const u16* wp = W0 + grow * 1024 + koff;
    const u16* xpt = X0 + (long)(bh * 16 + (l & 15)) * x0ld + koff;
    for (int ks = 0; ks < 16; ks += 8) {
      uint4 av[8], bv[8];
#pragma unroll
      for (int uu = 0; uu < 8; ++uu) {
        av[uu] = *(const uint4*)(wp + (long)(ks + uu) * 32);
        bv[uu] = *(const uint4*)(xpt + (long)(ks + uu) * 32);
      }
#pragma unroll
      for (int uu = 0; uu < 8; ++uu) acc = bmfma(av[uu], bv[uu], acc);
    }
  }
  if (X1) {
    const u16* wp = W1 + grow * 1024 + koff;
    const u16* xpt = X1 + (long)(bh * 16 + (l & 15)) * x1ld + koff;
    for (int ks = 0; ks < 16; ks += 8) {
      uint4 av[8], bv[8];
#pragma unroll
      for (int uu = 0; uu < 8; ++uu) {
        av[uu] = *(const uint4*)(wp + (long)(ks + uu) * 32);
        bv[uu] = *(const uint4*)(xpt + (long)(ks + uu) * 32);
      }
#pragma unroll
      for (int uu = 0; uu < 8; ++uu) acc = bmfma(av[uu], bv[uu], acc);
    }
  }
  __syncthreads();
  if (kh) *(f32x4*)&red[(bh * 64 + l) * 4] = acc;
  __syncthreads();
  if (!kh) {
    f32x4 o = *(f32x4*)&red[(bh * 64 + l) * 4];
    const int jout = j0 + kg;
    const int batch = bh * 16 + (l & 15);
    float g[4];
#pragma unroll
    for (int r = 0; r < 4; ++r) {
      float gg = acc[r] + o[r] + biasA[r * 1024 + jout];
      if (biasB) gg += biasB[r * 1024 + jout];
      if (biasC) gg += biasC[r * 1024 + jout];
      if (XP) gg += bf2f(XP[(long)batch * xpld + r * 1024 + jout]);
      g[r] = gg;
    }
    float iv = sigf(g[0]), fv = sigf(g[1]), gv = tanhf(g[2]), ov = sigf(g[3]);
    float co = cin ? cin[(long)batch * cld + jout] : 0.0f;
    float c = fv * co + iv * gv;
    float h = ov * tanhf(c);
    cout[(long)batch * 1024 + jout] = c;
    cstore2(&hout[(long)batch * hld + jout], f2bf(h));
    if (houtf) houtf[(long)batch * hfld + jout] = h;
  }
}

// ---------------- persistent conductor ----------------
struct CondArgs {
  const u16 *c0h, *c1w, *c1h, *tvecb;
  const float* tvec;
  u16 *yc0b, *embb;
  float* embf;
  float *cc0, *cc1;
  const float *b0i, *b0h, *b1i, *b1h;
  unsigned* bar;
};
__global__ __launch_bounds__(256) void cond_coop(CondArgs A) {
  __shared__ __align__(16) float red[512];
  const int j0 = blockIdx.x * 4;
  const int tid = threadIdx.x;
  int bi = 0;
  for (int u = 0; u < NU; ++u) {
    cell1024(j0, tid, red,
             u ? A.yc0b + (long)(u - 1) * 32 * 1024 : A.tvecb, u ? 1024 : 4096, A.c0h,
             nullptr, 0, nullptr,
             nullptr, 0,
             A.b0i, A.b0h, nullptr,
             u ? A.cc0 : A.tvec + 2048, u ? 1024 : 4096, A.cc0,
             A.yc0b + (long)u * 32 * 1024, 1024, nullptr, 0);
    gbar(A.bar + (long)(bi++) * BSTRIDE, 32);
    cell1024(j0, tid, red,
             A.yc0b + (long)u * 32 * 1024, 1024, A.c1w,
             u ? A.embb + (long)(u - 1) * 32 * 1024 : A.tvecb + 1024, u ? 1024 : 4096, A.c1h,
             nullptr, 0,
             A.b1i, A.b1h, nullptr,
             u ? A.cc1 : A.tvec + 3072, u ? 1024 : 4096, A.cc1,
             A.embb + (long)u * 32 * 1024, 1024, A.embf + (long)u * 32 * 1024, 1024);
    if (u < NU - 1) gbar(A.bar + (long)(bi++) * BSTRIDE, 32);
  }
}

// ---------------- persistent hierarchical decoder ----------------
struct DecArgs {
  const u16 *d1h, *wfuse, *d2w, *d2h, *xeb, *sallb;
  const float* sall;
  u16 *dh1all, *dh2all;   // rolling [64][32][1024]
  float *dc1, *dc2;
  const float *bfuse, *b1h, *b2i, *b2h;
  unsigned* bar;
};
__global__ __launch_bounds__(256) void dec_coop(DecArgs A) {
  __shared__ __align__(16) float red[512];
  const int j0 = blockIdx.x * 4;
  const int tid = threadIdx.x;
  int bi = 0;
  for (int t = 0; t < TT; ++t) {
    const int u = t >> 4, sg = t & 15;
    cell1024(j0, tid, red,
             sg ? A.dh1all + (long)(t - 1) * 32 * 1024 : A.sallb + (long)u * 32 * 4096,
             sg ? 1024 : 4096, A.d1h,
             t ? A.dh2all + (long)(t - 1) * 32 * 1024 : nullptr, 1024, A.wfuse,
             A.xeb + (long)u * 32 * 4096, 4096,
             A.b1h, t ? A.bfuse : nullptr, nullptr,
             sg ? A.dc1 : A.sall + (long)u * 32 * 4096 + 2048, sg ? 1024 : 4096, A.dc1,
             A.dh1all + (long)t * 32 * 1024, 1024, nullptr, 0);
    gbar(A.bar + (long)(bi++) * BSTRIDE, 32);
    cell1024(j0, tid, red,
             A.dh1all + (long)t * 32 * 1024, 1024, A.d2w,
             sg ? A.dh2all + (long)(t - 1) * 32 * 1024 : A.sallb + (long)u * 32 * 4096 + 1024,
             sg ? 1024 : 4096, A.d2h,
             nullptr, 0,
             A.b2i, A.b2h, nullptr,
             sg ? A.dc2 : A.sall + (long)u * 32 * 4096 + 3072, sg ? 1024 : 4096, A.dc2,
             A.dh2all + (long)t * 32 * 1024, 1024, nullptr, 0);
    if (t < TT - 1) gbar(A.bar + (long)(bi++) * BSTRIDE, 32);
  }
}

// ---------------- final p = dh2all @ w4^T + b4 -> out ----------------
__global__ __launch_bounds__(256) void proj_all(const u16* __restrict__ dh2all,
                                                const u16* __restrict__ w4b,
                                                const float* __restrict__ b4,
                                                float* __restrict__ out) {
  __shared__ u16 hs[8 * 1024];
  const int r0 = blockIdx.x * 8;
  for (int e = threadIdx.x; e < 1024; e += 256)
    ((uint4*)hs)[e] = ((const uint4*)(dh2all + (long)r0 * 1024))[e];
  __syncthreads();
  for (int o = threadIdx.x; o < 8 * INPW; o += 256) {
    int rr = o / INPW, n = o % INPW;
    const u16* wr = w4b + (long)n * 1024;
    const u16* hr = hs + rr * 1024;
    float s = 0.0f;
    for (int k = 0; k < 1024; ++k) s += bf2f(hr[k]) * bf2f(wr[k]);
    int row = r0 + rr;
    int tt = row >> 5, b = row & 31;
    out[((long)b * TT + tt) * INPW + n] = s + b4[n];
  }
}

// =====================================================================
extern "C" void kernel_launch(void* const* d_in, const int* in_sizes, int n_in,
                              void* d_out, int out_size, void* d_ws, size_t ws_size,
                              hipStream_t stream) {
  (void)in_sizes; (void)n_in; (void)out_size;
  const float* x        = (const float*)d_in[0];
  const float* eps      = (const float*)d_in[1];
  const float* e0f_wih  = (const float*)d_in[2];
  const float* e0f_whh  = (const float*)d_in[3];
  const float* e0f_bih  = (const float*)d_in[4];
  const float* e0f_bhh  = (const float*)d_in[5];
  const float* e0b_wih  = (const float*)d_in[6];
  const float* e0b_whh  = (const float*)d_in[7];
  const float* e0b_bih  = (const float*)d_in[8];
  const float* e0b_bhh  = (const float*)d_in[9];
  const float* e1f_wih  = (const float*)d_in[10];
  const float* e1f_whh  = (const float*)d_in[11];
  const float* e1f_bih  = (const float*)d_in[12];
  const float* e1f_bhh  = (const float*)d_in[13];
  const float* e1b_wih  = (const float*)d_in[14];
  const float* e1b_whh  = (const float*)d_in[15];
  const float* e1b_bih  = (const float*)d_in[16];
  const float* e1b_bhh  = (const float*)d_in[17];
  const float* wm  = (const float*)d_in[18];
  const float* bm  = (const float*)d_in[19];
  const float* wsw = (const float*)d_in[20];
  const float* bsv = (const float*)d_in[21];
  const float* w2  = (const float*)d_in[22];
  const float* b2  = (const float*)d_in[23];
  const float* c0_whh = (const float*)d_in[25];
  const float* c0_bih = (const float*)d_in[26];
  const float* c0_bhh = (const float*)d_in[27];
  const float* c1_wih = (const float*)d_in[28];
  const float* c1_whh = (const float*)d_in[29];
  const float* c1_bih = (const float*)d_in[30];
  const float* c1_bhh = (const float*)d_in[31];
  const float* w3 = (const float*)d_in[32];
  const float* b3 = (const float*)d_in[33];
  const float* d1_wih = (const float*)d_in[34];
  const float* d1_whh = (const float*)d_in[35];
  const float* d1_bih = (const float*)d_in[36];
  const float* d1_bhh = (const float*)d_in[37];
  const float* d2_wih = (const float*)d_in[38];
  const float* d2_whh = (const float*)d_in[39];
  const float* d2_bih = (const float*)d_in[40];
  const float* d2_bhh = (const float*)d_in[41];
  const float* w4 = (const float*)d_in[42];
  const float* b4 = (const float*)d_in[43];

  float* out = (float*)d_out;
  float* zm_out = out + (size_t)BB * TT * INPW;
  float* zs_out = zm_out + BB * NZ;

  char* wbase = (char*)d_ws;
  size_t cur = 0;
  auto AL = [&](size_t bytes) -> void* {
    void* p = wbase + cur;
    cur = (cur + bytes + 255) & ~(size_t)255;
    return p;
  };
  u16* xb    = (u16*)AL(2048L * 128 * 2);
  u16* e0wf  = (u16*)AL(8192L * 128 * 2);
  u16* e0wb  = (u16*)AL(8192L * 128 * 2);
  u16* e0hf  = (u16*)AL(8192L * 2048 * 2);
  u16* e0hb  = (u16*)AL(8192L * 2048 * 2);
  u16* e1wf  = (u16*)AL(8192L * 4096 * 2);
  u16* e1wb  = (u16*)AL(8192L * 4096 * 2);
  u16* e1hf  = (u16*)AL(8192L * 2048 * 2);
  u16* e1hb  = (u16*)AL(8192L * 2048 * 2);
  u16* c0h   = (u16*)AL(4096L * 1024 * 2);
  u16* c1w   = (u16*)AL(4096L * 1024 * 2);
  u16* c1h   = (u16*)AL(4096L * 1024 * 2);
  u16* d1we  = (u16*)AL(4096L * 1024 * 2);
  u16* d1wp  = (u16*)AL(4096L * 128 * 2);
  u16* d1h   = (u16*)AL(4096L * 1024 * 2);
  u16* d2w   = (u16*)AL(4096L * 1024 * 2);
  u16* d2h   = (u16*)AL(4096L * 1024 * 2);
  u16* w4b   = (u16*)AL(90L * 1024 * 2);
  u16* w4tb  = (u16*)AL(1024L * 128 * 2);
  u16* wfuse = (u16*)AL(4096L * 1024 * 2);
  float* bfuse = (float*)AL(4096L * 4);
  u16* xp0f  = (u16*)AL(2048L * 8192 * 2);
  u16* xp0b  = (u16*)AL(2048L * 8192 * 2);
  u16* y0b   = (u16*)AL(2048L * 4096 * 2);
  u16* xp1f  = (u16*)AL(2048L * 8192 * 2);
  u16* xp1b  = (u16*)AL(2048L * 8192 * 2);
  u16* h1af  = (u16*)AL(64L * 32 * 2048 * 2);
  u16* h1ab  = (u16*)AL(64L * 32 * 2048 * 2);
  u16* tvecb = (u16*)AL(32L * 4096 * 2);
  u16* yc0b  = (u16*)AL(4L * 32 * 1024 * 2);
  u16* embb  = (u16*)AL(4L * 32 * 1024 * 2);
  u16* sallb = (u16*)AL(128L * 4096 * 2);
  u16* xeb   = (u16*)AL(128L * 4096 * 2);
  u16* dh1all= (u16*)AL(64L * 32 * 1024 * 2);
  u16* dh2all= (u16*)AL(64L * 32 * 1024 * 2);
  float* c0f_ = (float*)AL(32L * 2048 * 4);
  float* c0b_ = (float*)AL(32L * 2048 * 4);
  float* c1f_ = (float*)AL(32L * 2048 * 4);
  float* c1b_ = (float*)AL(32L * 2048 * 4);
  float* htb  = (float*)AL(32L * 4096 * 4);
  float* zbuf = (float*)AL(32L * 512 * 4);
  float* tvec = (float*)AL(32L * 4096 * 4);
  float* cc0  = (float*)AL(32L * 1024 * 4);
  float* cc1  = (float*)AL(32L * 1024 * 4);
  float* embf = (float*)AL(128L * 1024 * 4);
  float* sall = (float*)AL(128L * 4096 * 4);
  float* dc1  = (float*)AL(32L * 1024 * 4);
  float* dc2  = (float*)AL(32L * 1024 * 4);
  unsigned* barp = (unsigned*)AL(420L * BSTRIDE * 4);
  if (cur > ws_size) return;

  // barrier regions: enc0 @0 (128 slots), enc1 @128, cond @256 (16), dec @280 (128)
  unsigned* bar_enc0 = barp;
  unsigned* bar_enc1 = barp + 128L * BSTRIDE;
  unsigned* bar_cond = barp + 256L * BSTRIDE;
  unsigned* bar_dec  = barp + 280L * BSTRIDE;

  // ---- conversions ----
  auto cf = [&](const float* s, u16* d, long n) {
    cvt_flat<<<dim3((unsigned)((n / 4 + 255) / 256)), 256, 0, stream>>>(s, d, n);
  };
  cf(e0f_whh, e0hf, 8192L * 2048);
  cf(e0b_whh, e0hb, 8192L * 2048);
  cf(e1f_wih, e1wf, 8192L * 4096);
  cf(e1b_wih, e1wb, 8192L * 4096);
  cf(e1f_whh, e1hf, 8192L * 2048);
  cf(e1b_whh, e1hb, 8192L * 2048);
  cf(c0_whh, c0h, 4096L * 1024);
  cf(c1_wih, c1w, 4096L * 1024);
  cf(c1_whh, c1h, 4096L * 1024);
  cf(d1_whh, d1h, 4096L * 1024);
  cf(d2_wih, d2w, 4096L * 1024);
  cf(d2_whh, d2h, 4096L * 1024);
  cf(w4, w4b, 90L * 1024);
  cvt_pad<<<dim3(1, 8192), 128, 0, stream>>>(e0f_wih, 90, 90, e0wf, 128, 8192);
  cvt_pad<<<dim3(1, 8192), 128, 0, stream>>>(e0b_wih, 90, 90, e0wb, 128, 8192);
  cvt_pad<<<dim3(4, 4096), 256, 0, stream>>>(d1_wih, 1114, 1024, d1we, 1024, 4096);
  cvt_pad<<<dim3(1, 4096), 128, 0, stream>>>(d1_wih + 1024, 1114, 90, d1wp, 128, 4096);
  xcvt<<<dim3(2048), 128, 0, stream>>>(x, xb);
  w4t_k<<<dim3(1024), 128, 0, stream>>>(w4, w4tb);
  bfuse_k<<<dim3(16), 256, 0, stream>>>(d1_wih, b4, bfuse);
  hipMemsetAsync(barp, 0, 420L * BSTRIDE * 4, stream);

  gemm_bf<<<dim3(32, 8), 256, 0, stream>>>(d1wp, 128, w4tb, 128, nullptr, wfuse, 1024, 128);
  gemm_bf<<<dim3(16, 64), 256, 0, stream>>>(xb, 128, e0wf, 128, e0f_bih, xp0f, 8192, 128);
  gemm_bf<<<dim3(16, 64), 256, 0, stream>>>(xb, 128, e0wb, 128, e0b_bih, xp0b, 8192, 128);

  // ---- encoder layer 0 ----
  {
    EncArgs ea{};
    ea.whh[0] = e0hf; ea.whh[1] = e0hb;
    ea.xp[0] = xp0f; ea.xp[1] = xp0b;
    ea.bhh[0] = e0f_bhh; ea.bhh[1] = e0b_bhh;
    ea.cst[0] = c0f_; ea.cst[1] = c0b_;
    ea.y0b = y0b; ea.h1a[0] = h1af; ea.h1a[1] = h1ab; ea.htb = htb;
    ea.bar = bar_enc0; ea.layer = 0;
    void* args[] = {&ea};
    hipLaunchCooperativeKernel((void*)enc_coop, dim3(256), dim3(256), args, 0, stream);
  }

  gemm_bf<<<dim3(16, 64), 256, 0, stream>>>(y0b, 4096, e1wf, 4096, e1f_bih, xp1f, 8192, 4096);
  gemm_bf<<<dim3(16, 64), 256, 0, stream>>>(y0b, 4096, e1wb, 4096, e1b_bih, xp1b, 8192, 4096);

  // ---- encoder layer 1 ----
  {
    EncArgs ea{};
    ea.whh[0] = e1hf; ea.whh[1] = e1hb;
    ea.xp[0] = xp1f; ea.xp[1] = xp1b;
    ea.bhh[0] = e1f_bhh; ea.bhh[1] = e1b_bhh;
    ea.cst[0] = c1f_; ea.cst[1] = c1b_;
    ea.y0b = y0b; ea.h1a[0] = h1af; ea.h1a[1] = h1ab; ea.htb = htb;
    ea.bar = bar_enc1; ea.layer = 1;
    void* args[] = {&ea};
    hipLaunchCooperativeKernel((void*)enc_coop, dim3(256), dim3(256), args, 0, stream);
  }

  // ---- latent ----
  gemm128<<<dim3(1, 4), 256, 0, stream>>>(htb, 4096, wm, 4096, bm, zm_out, 512, 32, 4096, 0, nullptr);
  gemm128<<<dim3(1, 4), 256, 0, stream>>>(htb, 4096, wsw, 4096, bsv, zs_out, 512, 32, 4096, 2, nullptr);
  zcalc_kernel<<<dim3(64), 256, 0, stream>>>(zm_out, zs_out, eps, zbuf);
  gemm128<<<dim3(1, 32), 256, 0, stream>>>(zbuf, 512, w2, 512, b2, tvec, 4096, 32, 512, 1, tvecb);

  // ---- conductor ----
  {
    CondArgs ca{};
    ca.c0h = c0h; ca.c1w = c1w; ca.c1h = c1h;
    ca.tvecb = tvecb; ca.tvec = tvec;
    ca.yc0b = yc0b; ca.embb = embb; ca.embf = embf;
    ca.cc0 = cc0; ca.cc1 = cc1;
    ca.b0i = c0_bih; ca.b0h = c0_bhh; ca.b1i = c1_bih; ca.b1h = c1_bhh;
    ca.bar = bar_cond;
    void* args[] = {&ca};
    hipLaunchCooperativeKernel((void*)cond_coop, dim3(256), dim3(256), args, 0, stream);
  }

  // ---- decoder prep ----
  gemm128<<<dim3(1, 32), 256, 0, stream>>>(embf, 1024, w3, 1024, b3, sall, 4096, 128, 1024, 1, sallb);
  gemm_bf<<<dim3(1, 32), 256, 0, stream>>>(embb, 1024, d1we, 1024, d1_bih, xeb, 4096, 1024);

  // ---- hierarchical decoder ----
  {
    DecArgs da{};
    da.d1h = d1h; da.wfuse = wfuse; da.d2w = d2w; da.d2h = d2h;
    da.xeb = xeb; da.sallb = sallb; da.sall = sall;
    da.dh1all = dh1all; da.dh2all = dh2all;
    da.dc1 = dc1; da.dc2 = dc2;
    da.bfuse = bfuse; da.b1h = d1_bhh; da.b2i = d2_bih; da.b2h = d2_bhh;
    da.bar = bar_dec;
    void* args[] = {&da};
    hipLaunchCooperativeKernel((void*)dec_coop, dim3(256), dim3(256), args, 0, stream);
  }

  // ---- outputs ----
  proj_all<<<dim3(256), 256, 0, stream>>>(dh2all, w4b, b4, out);
  softmax_kernel<<<dim3(BB * TT), 64, 0, stream>>>(out);
}

// Round 5
// 7521.256 us; speedup vs baseline: 2.1235x; 1.1449x over previous
//
#include <hip/hip_runtime.h>
#include <hip/hip_cooperative_groups.h>
#include <math.h>

#define BB 32
#define TT 64
#define INPW 90
#define NU 4
#define NH1 2048
#define NHC 1024
#define NHD 1024
#define NZ 512
#define BSTRIDE 160  // u32 per barrier slot (8 subs @ stride 16 + master @ 128)

typedef unsigned short u16;
typedef __attribute__((ext_vector_type(8))) short short8;
typedef __attribute__((ext_vector_type(4))) float f32x4;

__device__ __forceinline__ float sigf(float v) { return 1.0f / (1.0f + __expf(-v)); }

__device__ __forceinline__ u16 f2bf(float f) {
  unsigned u = __float_as_uint(f);
  unsigned r = (u + 0x7FFFu + ((u >> 16) & 1u)) >> 16;
  return (u16)r;
}
__device__ __forceinline__ float bf2f(u16 b) { return __uint_as_float(((unsigned)b) << 16); }

__device__ __forceinline__ f32x4 bmfma(uint4 a, uint4 b, f32x4 c) {
  return __builtin_amdgcn_mfma_f32_16x16x32_bf16(*(short8*)&a, *(short8*)&b, c, 0, 0, 0);
}

// ---- coherence helpers (cross-XCD, no cache flush) ----
__device__ __forceinline__ void cstore2(u16* p, u16 v) {
  unsigned vv = v;
  asm volatile("global_store_short %0, %1, off sc0 sc1" :: "v"(p), "v"(vv) : "memory");
}
__device__ __forceinline__ unsigned fload(const unsigned* p) {
  unsigned r;
  asm volatile("global_load_dword %0, %1, off sc0 sc1\n\ts_waitcnt vmcnt(0)"
               : "=v"(r) : "v"(p) : "memory");
  return r;
}
__device__ __forceinline__ void gbar(unsigned* base, unsigned subTarget) {
  asm volatile("s_waitcnt vmcnt(0)" ::: "memory");
  __syncthreads();
  if (threadIdx.x == 0) {
    unsigned old = atomicAdd(&base[(blockIdx.x & 7) << 4], 1u);
    if (old == subTarget - 1) atomicAdd(&base[128], 1u);
    while (fload(&base[128]) < 8u) __builtin_amdgcn_s_sleep(2);
  }
  __syncthreads();
}

// ---------------- conversion kernels ----------------
__global__ void cvt_flat(const float* __restrict__ s, u16* __restrict__ d, long n) {
  long i = ((long)blockIdx.x * 256 + threadIdx.x) * 4;
  if (i >= n) return;
  float4 v = *(const float4*)&s[i];
  d[i] = f2bf(v.x); d[i + 1] = f2bf(v.y); d[i + 2] = f2bf(v.z); d[i + 3] = f2bf(v.w);
}

__global__ void cvt_pad(const float* __restrict__ s, int sld, int cols,
                        u16* __restrict__ d, int dld, int rows) {
  int c = blockIdx.x * blockDim.x + threadIdx.x;
  int r = blockIdx.y;
  if (c >= dld) return;
  d[(long)r * dld + c] = (c < cols) ? f2bf(s[(long)r * sld + c]) : (u16)0;
}

__global__ void xcvt(const float* __restrict__ x, u16* __restrict__ xb) {
  int r = blockIdx.x, c = threadIdx.x;
  int b = r & 31, t = r >> 5;
  float v = (c < INPW) ? x[((long)b * TT + t) * INPW + c] : 0.0f;
  xb[(long)r * 128 + c] = f2bf(v);
}

__global__ void w4t_k(const float* __restrict__ w4, u16* __restrict__ w4tb) {
  int k = blockIdx.x, n = threadIdx.x;
  w4tb[(long)k * 128 + n] = (n < INPW) ? f2bf(w4[(long)n * NHD + k]) : (u16)0;
}

__global__ void bfuse_k(const float* __restrict__ d1_wih, const float* __restrict__ b4,
                        float* __restrict__ bfuse) {
  int r = blockIdx.x * 256 + threadIdx.x;
  if (r >= 4096) return;
  float s = 0.0f;
  for (int n = 0; n < INPW; ++n) s += d1_wih[(long)r * 1114 + 1024 + n] * b4[n];
  bfuse[r] = s;
}

// ---------------- bf16 MFMA GEMM ----------------
__global__ __launch_bounds__(256) void gemm_bf(
    const u16* __restrict__ A, int lda, const u16* __restrict__ Bw, int ldb,
    const float* __restrict__ bias, u16* __restrict__ C, int ldc, int K) {
  __shared__ u16 Asm[128 * 64];
  __shared__ u16 Bsm[128 * 64];
  const int tid = threadIdx.x;
  const int w = tid >> 6, q = (tid >> 4) & 3, ln = tid & 15;
  const int wm = w & 1, wn = w >> 1;
  const long am0 = (long)blockIdx.x * 128;
  const long bn0 = (long)blockIdx.y * 128;
  f32x4 acc[4][4] = {};
  const int srow = tid >> 3, ssl = tid & 7;
  const u16* Ap = A + (am0 + srow) * lda + ssl * 8;
  const u16* Bp = Bw + (bn0 + srow) * ldb + ssl * 8;
  uint4 va[4], vb[4];
  int soff[4];
#pragma unroll
  for (int i = 0; i < 4; ++i) {
    va[i] = *(const uint4*)(Ap + (long)i * 32 * lda);
    vb[i] = *(const uint4*)(Bp + (long)i * 32 * ldb);
    int r = srow + i * 32;
    soff[i] = r * 64 + ((ssl ^ (r & 7)) << 3);
  }
  int k0 = 0;
  for (;;) {
    __syncthreads();
#pragma unroll
    for (int i = 0; i < 4; ++i) {
      *(uint4*)&Asm[soff[i]] = va[i];
      *(uint4*)&Bsm[soff[i]] = vb[i];
    }
    __syncthreads();
    k0 += 64;
    if (k0 < K) {
#pragma unroll
      for (int i = 0; i < 4; ++i) {
        va[i] = *(const uint4*)(Ap + k0 + (long)i * 32 * lda);
        vb[i] = *(const uint4*)(Bp + k0 + (long)i * 32 * ldb);
      }
    }
#pragma unroll
    for (int kh = 0; kh < 2; ++kh) {
      short8 af[4], bg[4];
#pragma unroll
      for (int t = 0; t < 4; ++t) {
        int arr = wm * 64 + t * 16 + ln;
        af[t] = *(short8*)&Asm[arr * 64 + (((q + 4 * kh) ^ (arr & 7)) << 3)];
        int brr = wn * 64 + t * 16 + ln;
        bg[t] = *(short8*)&Bsm[brr * 64 + (((q + 4 * kh) ^ (brr & 7)) << 3)];
      }
#pragma unroll
      for (int mt = 0; mt < 4; ++mt)
#pragma unroll
        for (int nt = 0; nt < 4; ++nt)
          acc[mt][nt] = __builtin_amdgcn_mfma_f32_16x16x32_bf16(af[mt], bg[nt], acc[mt][nt], 0, 0, 0);
    }
    if (k0 >= K) break;
  }
#pragma unroll
  for (int nt = 0; nt < 4; ++nt) {
    long n = bn0 + wn * 64 + nt * 16 + ln;
    float bv = bias ? bias[n] : 0.0f;
#pragma unroll
    for (int mt = 0; mt < 4; ++mt) {
#pragma unroll
      for (int r = 0; r < 4; ++r) {
        long m = am0 + wm * 64 + mt * 16 + (q << 2) + r;
        C[m * ldc + n] = f2bf(acc[mt][nt][r] + bv);
      }
    }
  }
}

// ---------------- fp32 GEMM for latent path ----------------
__global__ __launch_bounds__(256) void gemm128(
    const float* __restrict__ A, int lda, const float* __restrict__ W, int ldw,
    const float* __restrict__ bias, float* __restrict__ C, int ldc,
    int M, int K, int act, u16* __restrict__ Cb) {
  __shared__ float As[16][132];
  __shared__ float Bs[16][132];
  const int tid = threadIdx.x;
  const int bm = blockIdx.x, bn = blockIdx.y;
  const int tm = tid & 15, tn = tid >> 4;
  float acc[8][8] = {};
  for (int k0 = 0; k0 < K; k0 += 16) {
#pragma unroll
    for (int it = 0; it < 2; ++it) {
      int e = it * 256 + tid;
      int r = e >> 2, c4 = (e & 3) * 4;
      int m = bm * 128 + r;
      float4 v = make_float4(0.f, 0.f, 0.f, 0.f);
      if (m < M) v = *(const float4*)&A[(long)m * lda + k0 + c4];
      As[c4 + 0][r] = v.x; As[c4 + 1][r] = v.y; As[c4 + 2][r] = v.z; As[c4 + 3][r] = v.w;
      int n = bn * 128 + r;
      float4 w = *(const float4*)&W[(long)n * ldw + k0 + c4];
      Bs[c4 + 0][r] = w.x; Bs[c4 + 1][r] = w.y; Bs[c4 + 2][r] = w.z; Bs[c4 + 3][r] = w.w;
    }
    __syncthreads();
#pragma unroll
    for (int kk = 0; kk < 16; ++kk) {
      float4 a0 = *(const float4*)&As[kk][tm * 8];
      float4 a1 = *(const float4*)&As[kk][tm * 8 + 4];
      float4 b0 = *(const float4*)&Bs[kk][tn * 8];
      float4 b1 = *(const float4*)&Bs[kk][tn * 8 + 4];
      float av[8] = {a0.x, a0.y, a0.z, a0.w, a1.x, a1.y, a1.z, a1.w};
      float bv[8] = {b0.x, b0.y, b0.z, b0.w, b1.x, b1.y, b1.z, b1.w};
#pragma unroll
      for (int i = 0; i < 8; ++i)
#pragma unroll
        for (int j = 0; j < 8; ++j)
          acc[i][j] += av[i] * bv[j];
    }
    __syncthreads();
  }
#pragma unroll
  for (int i = 0; i < 8; ++i) {
    int m = bm * 128 + tm * 8 + i;
    if (m >= M) continue;
#pragma unroll
    for (int j = 0; j < 8; ++j) {
      int n = bn * 128 + tn * 8 + j;
      float v = acc[i][j] + bias[n];
      if (act == 1) v = tanhf(v);
      else if (act == 2) v = log1pf(__expf(v));
      C[(long)m * ldc + n] = v;
      if (Cb) Cb[(long)m * ldc + n] = f2bf(v);
    }
  }
}

__global__ void zcalc_kernel(const float* __restrict__ zm, const float* __restrict__ zs,
                             const float* __restrict__ eps, float* __restrict__ z) {
  int e = blockIdx.x * 256 + threadIdx.x;
  if (e < BB * NZ) z[e] = zm[e] + eps[e] * zs[e];
}

__global__ void softmax_kernel(float* __restrict__ out) {
  long row = blockIdx.x;
  float* p = out + row * INPW;
  int lane = threadIdx.x;
  float v0 = (lane < INPW) ? p[lane] : -1e30f;
  float v1 = (lane + 64 < INPW) ? p[lane + 64] : -1e30f;
  float m = fmaxf(v0, v1);
#pragma unroll
  for (int off = 32; off > 0; off >>= 1) m = fmaxf(m, __shfl_xor(m, off));
  float e0 = (lane < INPW) ? __expf(v0 - m) : 0.0f;
  float e1 = (lane + 64 < INPW) ? __expf(v1 - m) : 0.0f;
  float sum = e0 + e1;
#pragma unroll
  for (int off = 32; off > 0; off >>= 1) sum += __shfl_xor(sum, off);
  float inv = 1.0f / sum;
  if (lane < INPW) p[lane] = e0 * inv;
  if (lane + 64 < INPW) p[lane + 64] = e1 * inv;
}

// ---------------- persistent encoder: LDS-resident weights, dirs sequential ----------------
// 256 blocks; block owns 8 hiddens (32 gate rows) of one dir at a time; 128 KiB LDS.
// Wave w: rt=w&1 (row-tile), bh=w>>1 (batch half). LDS slot (rt,s): lane-linear 16B frags.
struct EncArgs {
  const u16* whh[2];
  const u16* xp[2];
  const float* bhh[2];
  float* cst[2];
  u16* y0b;
  u16* h1a[2];
  float* htb;
  unsigned* bar;   // 126 slots: dir*63 + (s-1)
  int layer;
};

__global__ __launch_bounds__(256) void enc_coop(EncArgs A) {
  __shared__ u16 Wl[2 * 64 * 64 * 8];  // 128 KiB
  const int tid = threadIdx.x;
  const int w = tid >> 6, l = tid & 63;
  const int rt = w & 1, bh = w >> 1;
  const int kg = l >> 4, b0 = l & 15;
  const int j0 = blockIdx.x * 8;
  const int jout = j0 + rt * 4 + kg;
  const int batch = bh * 16 + b0;

  for (int dir = 0; dir < 2; ++dir) {
    __syncthreads();
    {
      const u16* W = A.whh[dir];
      for (int e = tid; e < 8192; e += 256) {
        int ert = e >> 12, es = (e >> 6) & 63, el = e & 63;
        int etr = el & 15;
        long gr = (long)(etr & 3) * 2048 + j0 + ert * 4 + (etr >> 2);
        *(uint4*)&Wl[((ert * 64 + es) * 64 + el) * 8] =
            *(const uint4*)&W[gr * 2048 + (el >> 4) * 8 + (long)es * 32];
      }
    }
    __syncthreads();
    const float* bhh = A.bhh[dir];
    float* cst = A.cst[dir];
    const u16* xp = A.xp[dir];
    const float bi0 = bhh[jout], bi1 = bhh[2048 + jout],
                bi2 = bhh[4096 + jout], bi3 = bhh[6144 + jout];
    for (int s = 0; s < 64; ++s) {
      if (s) gbar(A.bar + (long)(dir * 63 + (s - 1)) * BSTRIDE, 32);
      const int tt = dir ? 63 - s : s;
      f32x4 acc = {0.f, 0.f, 0.f, 0.f};
      if (s) {
        const u16* hb; long hld;
        if (A.layer == 0) {
          int tp = dir ? tt + 1 : tt - 1;
          hb = A.y0b + (long)tp * 32 * 4096 + dir * 2048;
          hld = 4096;
        } else {
          hb = A.h1a[dir] + (long)(s - 1) * 32 * 2048;
          hld = 2048;
        }
        const u16* xv = hb + (long)batch * hld + kg * 8;
        for (int ks = 0; ks < 64; ks += 8) {
          uint4 bv[8];
#pragma unroll
          for (int uu = 0; uu < 8; ++uu)
            bv[uu] = *(const uint4*)(xv + (long)(ks + uu) * 32);
          short8 av[8];
#pragma unroll
          for (int uu = 0; uu < 8; ++uu)
            av[uu] = *(const short8*)&Wl[((rt * 64 + ks + uu) * 64 + l) * 8];
#pragma unroll
          for (int uu = 0; uu < 8; ++uu)
            acc = __builtin_amdgcn_mfma_f32_16x16x32_bf16(av[uu], *(short8*)&bv[uu], acc, 0, 0, 0);
        }
      }
      const u16* xr = xp + ((long)tt * 32 + batch) * 8192;
      float g0 = acc[0] + bi0 + bf2f(xr[jout]);
      float g1 = acc[1] + bi1 + bf2f(xr[2048 + jout]);
      float g2 = acc[2] + bi2 + bf2f(xr[4096 + jout]);
      float g3 = acc[3] + bi3 + bf2f(xr[6144 + jout]);
      float iv = sigf(g0), fv = sigf(g1), gv = tanhf(g2), ov = sigf(g3);
      float co = s ? cst[batch * 2048 + jout] : 0.0f;
      float c = fv * co + iv * gv;
      float h = ov * tanhf(c);
      cst[batch * 2048 + jout] = c;
      if (A.layer == 0) {
        cstore2(&A.y0b[((long)tt * 32 + batch) * 4096 + dir * 2048 + jout], f2bf(h));
      } else {
        cstore2(&A.h1a[dir][((long)s * 32 + batch) * 2048 + jout], f2bf(h));
        if (s == 63) A.htb[batch * 4096 + dir * 2048 + jout] = h;
      }
    }
  }
}

// ---------------- H=1024 cell with LDS-resident weights ----------------
// Matrix m occupies LDS slots (m*2+kh)*16 + s, each slot = 64 lanes x 16 B.
__device__ __forceinline__ void stage_w1024(u16* Wl, int m, const u16* W, int j0, int tid) {
  for (int e = tid; e < 2048; e += 256) {
    int kh = e >> 10, s = (e >> 6) & 15, el = e & 63;
    int tr = el & 15;
    long gr = (long)(tr & 3) * 1024 + j0 + (tr >> 2);
    *(uint4*)&Wl[(((m * 2 + kh) * 16 + s) * 64 + el) * 8] =
        *(const uint4*)&W[gr * 1024 + kh * 512 + (el >> 4) * 8 + s * 32];
  }
}

__device__ __forceinline__ void cell1024_lds(
    const u16* Wl, int m0, int m1,
    int j0, int tid, float* red,
    const u16* X0, long x0ld,
    const u16* X1, long x1ld,
    const u16* XP, long xpld,
    const float* biasA, const float* biasB,
    const float* cin, long cld, float* cout,
    u16* hout, long hld, float* houtf, long hfld) {
  const int w = tid >> 6, l = tid & 63;
  const int bh = w & 1, kh = w >> 1;
  const int kg = l >> 4;
  const int koff = kh * 512 + kg * 8;
  const int batch = bh * 16 + (l & 15);
  f32x4 acc = {0.f, 0.f, 0.f, 0.f};
  if (X0) {
    const u16* xpt = X0 + (long)batch * x0ld + koff;
    const int sb = (m0 * 2 + kh) * 16;
#pragma unroll
    for (int ks = 0; ks < 16; ks += 8) {
      uint4 bv[8]; short8 av[8];
#pragma unroll
      for (int uu = 0; uu < 8; ++uu) bv[uu] = *(const uint4*)(xpt + (long)(ks + uu) * 32);
#pragma unroll
      for (int uu = 0; uu < 8; ++uu) av[uu] = *(const short8*)&Wl[((sb + ks + uu) * 64 + l) * 8];
#pragma unroll
      for (int uu = 0; uu < 8; ++uu)
        acc = __builtin_amdgcn_mfma_f32_16x16x32_bf16(av[uu], *(short8*)&bv[uu], acc, 0, 0, 0);
    }
  }
  if (X1) {
    const u16* xpt = X1 + (long)batch * x1ld + koff;
    const int sb = (m1 * 2 + kh) * 16;
#pragma unroll
    for (int ks = 0; ks < 16; ks += 8) {
      uint4 bv[8]; short8 av[8];
#pragma unroll
      for (int uu = 0; uu < 8; ++uu) bv[uu] = *(const uint4*)(xpt + (long)(ks + uu) * 32);
#pragma unroll
      for (int uu = 0; uu < 8; ++uu) av[uu] = *(const short8*)&Wl[((sb + ks + uu) * 64 + l) * 8];
#pragma unroll
      for (int uu = 0; uu < 8; ++uu)
        acc = __builtin_amdgcn_mfma_f32_16x16x32_bf16(av[uu], *(short8*)&bv[uu], acc, 0, 0, 0);
    }
  }
  __syncthreads();
  if (kh) *(f32x4*)&red[(bh * 64 + l) * 4] = acc;
  __syncthreads();
  if (!kh) {
    f32x4 o = *(f32x4*)&red[(bh * 64 + l) * 4];
    const int jout = j0 + kg;
    float g[4];
#pragma unroll
    for (int r = 0; r < 4; ++r) {
      float gg = acc[r] + o[r] + biasA[r * 1024 + jout];
      if (biasB) gg += biasB[r * 1024 + jout];
      if (XP) gg += bf2f(XP[(long)batch * xpld + r * 1024 + jout]);
      g[r] = gg;
    }
    float iv = sigf(g[0]), fv = sigf(g[1]), gv = tanhf(g[2]), ov = sigf(g[3]);
    float co = cin ? cin[(long)batch * cld + jout] : 0.0f;
    float c = fv * co + iv * gv;
    float h = ov * tanhf(c);
    cout[(long)batch * 1024 + jout] = c;
    cstore2(&hout[(long)batch * hld + jout], f2bf(h));
    if (houtf) houtf[(long)batch * hfld + jout] = h;
  }
}

// ---------------- persistent conductor ----------------
struct CondArgs {
  const u16 *c0h, *c1w, *c1h, *tvecb;
  const float* tvec;
  u16 *yc0b, *embb;
  float* embf;
  float *cc0, *cc1;
  const float *b0i, *b0h, *b1i, *b1h;
  unsigned* bar;
};
__global__ __launch_bounds__(256) void cond_coop(CondArgs A) {
  __shared__ u16 Wl[3 * 32 * 512];   // 96 KiB
  __shared__ __align__(16) float red[512];
  const int j0 = blockIdx.x * 4;
  const int tid = threadIdx.x;
  stage_w1024(Wl, 0, A.c0h, j0, tid);
  stage_w1024(Wl, 1, A.c1w, j0, tid);
  stage_w1024(Wl, 2, A.c1h, j0, tid);
  __syncthreads();
  int bi = 0;
  for (int u = 0; u < NU; ++u) {
    cell1024_lds(Wl, 0, -1, j0, tid, red,
                 u ? A.yc0b + (long)(u - 1) * 32 * 1024 : A.tvecb, u ? 1024 : 4096,
                 nullptr, 0,
                 nullptr, 0,
                 A.b0i, A.b0h,
                 u ? A.cc0 : A.tvec + 2048, u ? 1024 : 4096, A.cc0,
                 A.yc0b + (long)u * 32 * 1024, 1024, nullptr, 0);
    gbar(A.bar + (long)(bi++) * BSTRIDE, 32);
    cell1024_lds(Wl, 1, 2, j0, tid, red,
                 A.yc0b + (long)u * 32 * 1024, 1024,
                 u ? A.embb + (long)(u - 1) * 32 * 1024 : A.tvecb + 1024, u ? 1024 : 4096,
                 nullptr, 0,
                 A.b1i, A.b1h,
                 u ? A.cc1 : A.tvec + 3072, u ? 1024 : 4096, A.cc1,
                 A.embb + (long)u * 32 * 1024, 1024, A.embf + (long)u * 32 * 1024, 1024);
    if (u < NU - 1) gbar(A.bar + (long)(bi++) * BSTRIDE, 32);
  }
}

// ---------------- persistent hierarchical decoder ----------------
struct DecArgs {
  const u16 *d1h, *wfuse, *d2w, *d2h, *xeb, *sallb;
  const float* sall;
  u16 *dh1all, *dh2all;
  float *dc1, *dc2;
  const float *bfuse, *b1h, *b2i, *b2h;
  unsigned* bar;
};
__global__ __launch_bounds__(256) void dec_coop(DecArgs A) {
  __shared__ u16 Wl[4 * 32 * 512];   // 128 KiB
  __shared__ __align__(16) float red[512];
  const int j0 = blockIdx.x * 4;
  const int tid = threadIdx.x;
  stage_w1024(Wl, 0, A.d1h, j0, tid);
  stage_w1024(Wl, 1, A.wfuse, j0, tid);
  stage_w1024(Wl, 2, A.d2w, j0, tid);
  stage_w1024(Wl, 3, A.d2h, j0, tid);
  __syncthreads();
  int bi = 0;
  for (int t = 0; t < TT; ++t) {
    const int u = t >> 4, sg = t & 15;
    cell1024_lds(Wl, 0, 1, j0, tid, red,
                 sg ? A.dh1all + (long)(t - 1) * 32 * 1024 : A.sallb + (long)u * 32 * 4096,
                 sg ? 1024 : 4096,
                 t ? A.dh2all + (long)(t - 1) * 32 * 1024 : nullptr, 1024,
                 A.xeb + (long)u * 32 * 4096, 4096,
                 A.b1h, t ? A.bfuse : nullptr,
                 sg ? A.dc1 : A.sall + (long)u * 32 * 4096 + 2048, sg ? 1024 : 4096, A.dc1,
                 A.dh1all + (long)t * 32 * 1024, 1024, nullptr, 0);
    gbar(A.bar + (long)(bi++) * BSTRIDE, 32);
    cell1024_lds(Wl, 2, 3, j0, tid, red,
                 A.dh1all + (long)t * 32 * 1024, 1024,
                 sg ? A.dh2all + (long)(t - 1) * 32 * 1024 : A.sallb + (long)u * 32 * 4096 + 1024,
                 sg ? 1024 : 4096,
                 nullptr, 0,
                 A.b2i, A.b2h,
                 sg ? A.dc2 : A.sall + (long)u * 32 * 4096 + 3072, sg ? 1024 : 4096, A.dc2,
                 A.dh2all + (long)t * 32 * 1024, 1024, nullptr, 0);
    if (t < TT - 1) gbar(A.bar + (long)(bi++) * BSTRIDE, 32);
  }
}

// ---------------- final p = dh2all @ w4^T + b4 -> out ----------------
__global__ __launch_bounds__(256) void proj_all(const u16* __restrict__ dh2all,
                                                const u16* __restrict__ w4b,
                                                const float* __restrict__ b4,
                                                float* __restrict__ out) {
  __shared__ u16 hs[8 * 1024];
  const int r0 = blockIdx.x * 8;
  for (int e = threadIdx.x; e < 1024; e += 256)
    ((uint4*)hs)[e] = ((const uint4*)(dh2all + (long)r0 * 1024))[e];
  __syncthreads();
  for (int o = threadIdx.x; o < 8 * INPW; o += 256) {
    int rr = o / INPW, n = o % INPW;
    const u16* wr = w4b + (long)n * 1024;
    const u16* hr = hs + rr * 1024;
    float s = 0.0f;
    for (int k = 0; k < 1024; ++k) s += bf2f(hr[k]) * bf2f(wr[k]);
    int row = r0 + rr;
    int tt = row >> 5, b = row & 31;
    out[((long)b * TT + tt) * INPW + n] = s + b4[n];
  }
}

// =====================================================================
extern "C" void kernel_launch(void* const* d_in, const int* in_sizes, int n_in,
                              void* d_out, int out_size, void* d_ws, size_t ws_size,
                              hipStream_t stream) {
  (void)in_sizes; (void)n_in; (void)out_size;
  const float* x        = (const float*)d_in[0];
  const float* eps      = (const float*)d_in[1];
  const float* e0f_wih  = (const float*)d_in[2];
  const float* e0f_whh  = (const float*)d_in[3];
  const float* e0f_bih  = (const float*)d_in[4];
  const float* e0f_bhh  = (const float*)d_in[5];
  const float* e0b_wih  = (const float*)d_in[6];
  const float* e0b_whh  = (const float*)d_in[7];
  const float* e0b_bih  = (const float*)d_in[8];
  const float* e0b_bhh  = (const float*)d_in[9];
  const float* e1f_wih  = (const float*)d_in[10];
  const float* e1f_whh  = (const float*)d_in[11];
  const float* e1f_bih  = (const float*)d_in[12];
  const float* e1f_bhh  = (const float*)d_in[13];
  const float* e1b_wih  = (const float*)d_in[14];
  const float* e1b_whh  = (const float*)d_in[15];
  const float* e1b_bih  = (const float*)d_in[16];
  const float* e1b_bhh  = (const float*)d_in[17];
  const float* wm  = (const float*)d_in[18];
  const float* bm  = (const float*)d_in[19];
  const float* wsw = (const float*)d_in[20];
  const float* bsv = (const float*)d_in[21];
  const float* w2  = (const float*)d_in[22];
  const float* b2  = (const float*)d_in[23];
  const float* c0_whh = (const float*)d_in[25];
  const float* c0_bih = (const float*)d_in[26];
  const float* c0_bhh = (const float*)d_in[27];
  const float* c1_wih = (const float*)d_in[28];
  const float* c1_whh = (const float*)d_in[29];
  const float* c1_bih = (const float*)d_in[30];
  const float* c1_bhh = (const float*)d_in[31];
  const float* w3 = (const float*)d_in[32];
  const float* b3 = (const float*)d_in[33];
  const float* d1_wih = (const float*)d_in[34];
  const float* d1_whh = (const float*)d_in[35];
  const float* d1_bih = (const float*)d_in[36];
  const float* d1_bhh = (const float*)d_in[37];
  const float* d2_wih = (const float*)d_in[38];
  const float* d2_whh = (const float*)d_in[39];
  const float* d2_bih = (const float*)d_in[40];
  const float* d2_bhh = (const float*)d_in[41];
  const float* w4 = (const float*)d_in[42];
  const float* b4 = (const float*)d_in[43];

  float* out = (float*)d_out;
  float* zm_out = out + (size_t)BB * TT * INPW;
  float* zs_out = zm_out + BB * NZ;

  char* wbase = (char*)d_ws;
  size_t cur = 0;
  auto AL = [&](size_t bytes) -> void* {
    void* p = wbase + cur;
    cur = (cur + bytes + 255) & ~(size_t)255;
    return p;
  };
  u16* xb    = (u16*)AL(2048L * 128 * 2);
  u16* e0wf  = (u16*)AL(8192L * 128 * 2);
  u16* e0wb  = (u16*)AL(8192L * 128 * 2);
  u16* e0hf  = (u16*)AL(8192L * 2048 * 2);
  u16* e0hb  = (u16*)AL(8192L * 2048 * 2);
  u16* e1wf  = (u16*)AL(8192L * 4096 * 2);
  u16* e1wb  = (u16*)AL(8192L * 4096 * 2);
  u16* e1hf  = (u16*)AL(8192L * 2048 * 2);
  u16* e1hb  = (u16*)AL(8192L * 2048 * 2);
  u16* c0h   = (u16*)AL(4096L * 1024 * 2);
  u16* c1w   = (u16*)AL(4096L * 1024 * 2);
  u16* c1h   = (u16*)AL(4096L * 1024 * 2);
  u16* d1we  = (u16*)AL(4096L * 1024 * 2);
  u16* d1wp  = (u16*)AL(4096L * 128 * 2);
  u16* d1h   = (u16*)AL(4096L * 1024 * 2);
  u16* d2w   = (u16*)AL(4096L * 1024 * 2);
  u16* d2h   = (u16*)AL(4096L * 1024 * 2);
  u16* w4b   = (u16*)AL(90L * 1024 * 2);
  u16* w4tb  = (u16*)AL(1024L * 128 * 2);
  u16* wfuse = (u16*)AL(4096L * 1024 * 2);
  float* bfuse = (float*)AL(4096L * 4);
  u16* xp0f  = (u16*)AL(2048L * 8192 * 2);
  u16* xp0b  = (u16*)AL(2048L * 8192 * 2);
  u16* y0b   = (u16*)AL(2048L * 4096 * 2);
  u16* xp1f  = (u16*)AL(2048L * 8192 * 2);
  u16* xp1b  = (u16*)AL(2048L * 8192 * 2);
  u16* h1af  = (u16*)AL(64L * 32 * 2048 * 2);
  u16* h1ab  = (u16*)AL(64L * 32 * 2048 * 2);
  u16* tvecb = (u16*)AL(32L * 4096 * 2);
  u16* yc0b  = (u16*)AL(4L * 32 * 1024 * 2);
  u16* embb  = (u16*)AL(4L * 32 * 1024 * 2);
  u16* sallb = (u16*)AL(128L * 4096 * 2);
  u16* xeb   = (u16*)AL(128L * 4096 * 2);
  u16* dh1all= (u16*)AL(64L * 32 * 1024 * 2);
  u16* dh2all= (u16*)AL(64L * 32 * 1024 * 2);
  float* c0f_ = (float*)AL(32L * 2048 * 4);
  float* c0b_ = (float*)AL(32L * 2048 * 4);
  float* c1f_ = (float*)AL(32L * 2048 * 4);
  float* c1b_ = (float*)AL(32L * 2048 * 4);
  float* htb  = (float*)AL(32L * 4096 * 4);
  float* zbuf = (float*)AL(32L * 512 * 4);
  float* tvec = (float*)AL(32L * 4096 * 4);
  float* cc0  = (float*)AL(32L * 1024 * 4);
  float* cc1  = (float*)AL(32L * 1024 * 4);
  float* embf = (float*)AL(128L * 1024 * 4);
  float* sall = (float*)AL(128L * 4096 * 4);
  float* dc1  = (float*)AL(32L * 1024 * 4);
  float* dc2  = (float*)AL(32L * 1024 * 4);
  unsigned* barp = (unsigned*)AL(400L * BSTRIDE * 4);
  if (cur > ws_size) return;

  // barrier regions: enc0 @0 (126), enc1 @128 (126), cond @256 (7), dec @264 (127)
  unsigned* bar_enc0 = barp;
  unsigned* bar_enc1 = barp + 128L * BSTRIDE;
  unsigned* bar_cond = barp + 256L * BSTRIDE;
  unsigned* bar_dec  = barp + 264L * BSTRIDE;

  // ---- conversions ----
  auto cf = [&](const float* s, u16* d, long n) {
    cvt_flat<<<dim3((unsigned)((n / 4 + 255) / 256)), 256, 0, stream>>>(s, d, n);
  };
  cf(e0f_whh, e0hf, 8192L * 2048);
  cf(e0b_whh, e0hb, 8192L * 2048);
  cf(e1f_wih, e1wf, 8192L * 4096);
  cf(e1b_wih, e1wb, 8192L * 4096);
  cf(e1f_whh, e1hf, 8192L * 2048);
  cf(e1b_whh, e1hb, 8192L * 2048);
  cf(c0_whh, c0h, 4096L * 1024);
  cf(c1_wih, c1w, 4096L * 1024);
  cf(c1_whh, c1h, 4096L * 1024);
  cf(d1_whh, d1h, 4096L * 1024);
  cf(d2_wih, d2w, 4096L * 1024);
  cf(d2_whh, d2h, 4096L * 1024);
  cf(w4, w4b, 90L * 1024);
  cvt_pad<<<dim3(1, 8192), 128, 0, stream>>>(e0f_wih, 90, 90, e0wf, 128, 8192);
  cvt_pad<<<dim3(1, 8192), 128, 0, stream>>>(e0b_wih, 90, 90, e0wb, 128, 8192);
  cvt_pad<<<dim3(4, 4096), 256, 0, stream>>>(d1_wih, 1114, 1024, d1we, 1024, 4096);
  cvt_pad<<<dim3(1, 4096), 128, 0, stream>>>(d1_wih + 1024, 1114, 90, d1wp, 128, 4096);
  xcvt<<<dim3(2048), 128, 0, stream>>>(x, xb);
  w4t_k<<<dim3(1024), 128, 0, stream>>>(w4, w4tb);
  bfuse_k<<<dim3(16), 256, 0, stream>>>(d1_wih, b4, bfuse);
  hipMemsetAsync(barp, 0, 400L * BSTRIDE * 4, stream);

  gemm_bf<<<dim3(32, 8), 256, 0, stream>>>(d1wp, 128, w4tb, 128, nullptr, wfuse, 1024, 128);
  gemm_bf<<<dim3(16, 64), 256, 0, stream>>>(xb, 128, e0wf, 128, e0f_bih, xp0f, 8192, 128);
  gemm_bf<<<dim3(16, 64), 256, 0, stream>>>(xb, 128, e0wb, 128, e0b_bih, xp0b, 8192, 128);

  // ---- encoder layer 0 ----
  {
    EncArgs ea{};
    ea.whh[0] = e0hf; ea.whh[1] = e0hb;
    ea.xp[0] = xp0f; ea.xp[1] = xp0b;
    ea.bhh[0] = e0f_bhh; ea.bhh[1] = e0b_bhh;
    ea.cst[0] = c0f_; ea.cst[1] = c0b_;
    ea.y0b = y0b; ea.h1a[0] = h1af; ea.h1a[1] = h1ab; ea.htb = htb;
    ea.bar = bar_enc0; ea.layer = 0;
    void* args[] = {&ea};
    hipLaunchCooperativeKernel((void*)enc_coop, dim3(256), dim3(256), args, 0, stream);
  }

  gemm_bf<<<dim3(16, 64), 256, 0, stream>>>(y0b, 4096, e1wf, 4096, e1f_bih, xp1f, 8192, 4096);
  gemm_bf<<<dim3(16, 64), 256, 0, stream>>>(y0b, 4096, e1wb, 4096, e1b_bih, xp1b, 8192, 4096);

  // ---- encoder layer 1 ----
  {
    EncArgs ea{};
    ea.whh[0] = e1hf; ea.whh[1] = e1hb;
    ea.xp[0] = xp1f; ea.xp[1] = xp1b;
    ea.bhh[0] = e1f_bhh; ea.bhh[1] = e1b_bhh;
    ea.cst[0] = c1f_; ea.cst[1] = c1b_;
    ea.y0b = y0b; ea.h1a[0] = h1af; ea.h1a[1] = h1ab; ea.htb = htb;
    ea.bar = bar_enc1; ea.layer = 1;
    void* args[] = {&ea};
    hipLaunchCooperativeKernel((void*)enc_coop, dim3(256), dim3(256), args, 0, stream);
  }

  // ---- latent ----
  gemm128<<<dim3(1, 4), 256, 0, stream>>>(htb, 4096, wm, 4096, bm, zm_out, 512, 32, 4096, 0, nullptr);
  gemm128<<<dim3(1, 4), 256, 0, stream>>>(htb, 4096, wsw, 4096, bsv, zs_out, 512, 32, 4096, 2, nullptr);
  zcalc_kernel<<<dim3(64), 256, 0, stream>>>(zm_out, zs_out, eps, zbuf);
  gemm128<<<dim3(1, 32), 256, 0, stream>>>(zbuf, 512, w2, 512, b2, tvec, 4096, 32, 512, 1, tvecb);

  // ---- conductor ----
  {
    CondArgs ca{};
    ca.c0h = c0h; ca.c1w = c1w; ca.c1h = c1h;
    ca.tvecb = tvecb; ca.tvec = tvec;
    ca.yc0b = yc0b; ca.embb = embb; ca.embf = embf;
    ca.cc0 = cc0; ca.cc1 = cc1;
    ca.b0i = c0_bih; ca.b0h = c0_bhh; ca.b1i = c1_bih; ca.b1h = c1_bhh;
    ca.bar = bar_cond;
    void* args[] = {&ca};
    hipLaunchCooperativeKernel((void*)cond_coop, dim3(256), dim3(256), args, 0, stream);
  }

  // ---- decoder prep ----
  gemm128<<<dim3(1, 32), 256, 0, stream>>>(embf, 1024, w3, 1024, b3, sall, 4096, 128, 1024, 1, sallb);
  gemm_bf<<<dim3(1, 32), 256, 0, stream>>>(embb, 1024, d1we, 1024, d1_bih, xeb, 4096, 1024);

  // ---- hierarchical decoder ----
  {
    DecArgs da{};
    da.d1h = d1h; da.wfuse = wfuse; da.d2w = d2w; da.d2h = d2h;
    da.xeb = xeb; da.sallb = sallb; da.sall = sall;
    da.dh1all = dh1all; da.dh2all = dh2all;
    da.dc1 = dc1; da.dc2 = dc2;
    da.bfuse = bfuse; da.b1h = d1_bhh; da.b2i = d2_bih; da.b2h = d2_bhh;
    da.bar = bar_dec;
    void* args[] = {&da};
    hipLaunchCooperativeKernel((void*)dec_coop, dim3(256), dim3(256), args, 0, stream);
  }

  // ---- outputs ----
  proj_all<<<dim3(256), 256, 0, stream>>>(dh2all, w4b, b4, out);
  softmax_kernel<<<dim3(BB * TT), 64, 0, stream>>>(out);
}

// Round 6
// 7378.984 us; speedup vs baseline: 2.1644x; 1.0193x over previous
//
#include <hip/hip_runtime.h>
#include <hip/hip_cooperative_groups.h>
#include <math.h>

#define BB 32
#define TT 64
#define INPW 90
#define NU 4
#define NH1 2048
#define NHC 1024
#define NHD 1024
#define NZ 512
#define BSTRIDE 160  // u32 per barrier slot (8 subs @ stride 16 + master @ 128)

typedef unsigned short u16;
typedef __attribute__((ext_vector_type(8))) short short8;
typedef __attribute__((ext_vector_type(4))) float f32x4;

__device__ __forceinline__ float sigf(float v) { return 1.0f / (1.0f + __expf(-v)); }

__device__ __forceinline__ u16 f2bf(float f) {
  unsigned u = __float_as_uint(f);
  unsigned r = (u + 0x7FFFu + ((u >> 16) & 1u)) >> 16;
  return (u16)r;
}
__device__ __forceinline__ float bf2f(u16 b) { return __uint_as_float(((unsigned)b) << 16); }

// ---- coherence helpers (cross-XCD, no cache flush) ----
__device__ __forceinline__ void cstore2(u16* p, u16 v) {
  unsigned vv = v;
  asm volatile("global_store_short %0, %1, off sc0 sc1" :: "v"(p), "v"(vv) : "memory");
}
__device__ __forceinline__ unsigned fload(const unsigned* p) {
  unsigned r;
  asm volatile("global_load_dword %0, %1, off sc0 sc1\n\ts_waitcnt vmcnt(0)"
               : "=v"(r) : "v"(p) : "memory");
  return r;
}
__device__ __forceinline__ void gbar(unsigned* base, unsigned subTarget) {
  asm volatile("s_waitcnt vmcnt(0)" ::: "memory");
  __syncthreads();
  if (threadIdx.x == 0) {
    unsigned old = atomicAdd(&base[(blockIdx.x & 7) << 4], 1u);
    if (old == subTarget - 1) atomicAdd(&base[128], 1u);
    while (fload(&base[128]) < 8u) __builtin_amdgcn_s_sleep(2);
  }
  __syncthreads();
}

// ---------------- conversion kernels ----------------
__global__ void cvt_flat(const float* __restrict__ s, u16* __restrict__ d, long n) {
  long i = ((long)blockIdx.x * 256 + threadIdx.x) * 4;
  if (i >= n) return;
  float4 v = *(const float4*)&s[i];
  d[i] = f2bf(v.x); d[i + 1] = f2bf(v.y); d[i + 2] = f2bf(v.z); d[i + 3] = f2bf(v.w);
}

__global__ void cvt_pad(const float* __restrict__ s, int sld, int cols,
                        u16* __restrict__ d, int dld, int rows) {
  int c = blockIdx.x * blockDim.x + threadIdx.x;
  int r = blockIdx.y;
  if (c >= dld) return;
  d[(long)r * dld + c] = (c < cols) ? f2bf(s[(long)r * sld + c]) : (u16)0;
}

__global__ void xcvt(const float* __restrict__ x, u16* __restrict__ xb) {
  int r = blockIdx.x, c = threadIdx.x;
  int b = r & 31, t = r >> 5;
  float v = (c < INPW) ? x[((long)b * TT + t) * INPW + c] : 0.0f;
  xb[(long)r * 128 + c] = f2bf(v);
}

__global__ void w4t_k(const float* __restrict__ w4, u16* __restrict__ w4tb) {
  int k = blockIdx.x, n = threadIdx.x;
  w4tb[(long)k * 128 + n] = (n < INPW) ? f2bf(w4[(long)n * NHD + k]) : (u16)0;
}

__global__ void bfuse_k(const float* __restrict__ d1_wih, const float* __restrict__ b4,
                        float* __restrict__ bfuse) {
  int r = blockIdx.x * 256 + threadIdx.x;
  if (r >= 4096) return;
  float s = 0.0f;
  for (int n = 0; n < INPW; ++n) s += d1_wih[(long)r * 1114 + 1024 + n] * b4[n];
  bfuse[r] = s;
}

// ---------------- bf16 MFMA GEMM ----------------
// mode 0: C[m*ldc+n]
// mode 1 (enc xp, N=8192): j=n&2047, g=n>>11 -> C[(( (m>>5)*256 + (j>>3) )*32 + (m&31))*32 + (j&7)*4 + g]
// mode 2 (dec xeb, N=4096): j=n&1023, g=n>>10 -> C[((j>>2)*128 + m)*16 + (j&3)*4 + g]
__global__ __launch_bounds__(256) void gemm_bf(
    const u16* __restrict__ A, int lda, const u16* __restrict__ Bw, int ldb,
    const float* __restrict__ bias, u16* __restrict__ C, int ldc, int K, int mode) {
  __shared__ u16 Asm[128 * 64];
  __shared__ u16 Bsm[128 * 64];
  const int tid = threadIdx.x;
  const int w = tid >> 6, q = (tid >> 4) & 3, ln = tid & 15;
  const int wm = w & 1, wn = w >> 1;
  const long am0 = (long)blockIdx.x * 128;
  const long bn0 = (long)blockIdx.y * 128;
  f32x4 acc[4][4] = {};
  const int srow = tid >> 3, ssl = tid & 7;
  const u16* Ap = A + (am0 + srow) * lda + ssl * 8;
  const u16* Bp = Bw + (bn0 + srow) * ldb + ssl * 8;
  uint4 va[4], vb[4];
  int soff[4];
#pragma unroll
  for (int i = 0; i < 4; ++i) {
    va[i] = *(const uint4*)(Ap + (long)i * 32 * lda);
    vb[i] = *(const uint4*)(Bp + (long)i * 32 * ldb);
    int r = srow + i * 32;
    soff[i] = r * 64 + ((ssl ^ (r & 7)) << 3);
  }
  int k0 = 0;
  for (;;) {
    __syncthreads();
#pragma unroll
    for (int i = 0; i < 4; ++i) {
      *(uint4*)&Asm[soff[i]] = va[i];
      *(uint4*)&Bsm[soff[i]] = vb[i];
    }
    __syncthreads();
    k0 += 64;
    if (k0 < K) {
#pragma unroll
      for (int i = 0; i < 4; ++i) {
        va[i] = *(const uint4*)(Ap + k0 + (long)i * 32 * lda);
        vb[i] = *(const uint4*)(Bp + k0 + (long)i * 32 * ldb);
      }
    }
#pragma unroll
    for (int kh = 0; kh < 2; ++kh) {
      short8 af[4], bg[4];
#pragma unroll
      for (int t = 0; t < 4; ++t) {
        int arr = wm * 64 + t * 16 + ln;
        af[t] = *(short8*)&Asm[arr * 64 + (((q + 4 * kh) ^ (arr & 7)) << 3)];
        int brr = wn * 64 + t * 16 + ln;
        bg[t] = *(short8*)&Bsm[brr * 64 + (((q + 4 * kh) ^ (brr & 7)) << 3)];
      }
#pragma unroll
      for (int mt = 0; mt < 4; ++mt)
#pragma unroll
        for (int nt = 0; nt < 4; ++nt)
          acc[mt][nt] = __builtin_amdgcn_mfma_f32_16x16x32_bf16(af[mt], bg[nt], acc[mt][nt], 0, 0, 0);
    }
    if (k0 >= K) break;
  }
#pragma unroll
  for (int nt = 0; nt < 4; ++nt) {
    long n = bn0 + wn * 64 + nt * 16 + ln;
    float bv = bias ? bias[n] : 0.0f;
#pragma unroll
    for (int mt = 0; mt < 4; ++mt) {
#pragma unroll
      for (int r = 0; r < 4; ++r) {
        long m = am0 + wm * 64 + mt * 16 + (q << 2) + r;
        long dst;
        if (mode == 0) {
          dst = m * ldc + n;
        } else if (mode == 1) {
          long j = n & 2047, g = n >> 11;
          dst = (((m >> 5) * 256 + (j >> 3)) * 32 + (m & 31)) * 32 + (j & 7) * 4 + g;
        } else {
          long j = n & 1023, g = n >> 10;
          dst = ((j >> 2) * 128 + m) * 16 + (j & 3) * 4 + g;
        }
        C[dst] = f2bf(acc[mt][nt][r] + bv);
      }
    }
  }
}

// ---------------- fp32 GEMM for latent path ----------------
__global__ __launch_bounds__(256) void gemm128(
    const float* __restrict__ A, int lda, const float* __restrict__ W, int ldw,
    const float* __restrict__ bias, float* __restrict__ C, int ldc,
    int M, int K, int act, u16* __restrict__ Cb) {
  __shared__ float As[16][132];
  __shared__ float Bs[16][132];
  const int tid = threadIdx.x;
  const int bm = blockIdx.x, bn = blockIdx.y;
  const int tm = tid & 15, tn = tid >> 4;
  float acc[8][8] = {};
  for (int k0 = 0; k0 < K; k0 += 16) {
#pragma unroll
    for (int it = 0; it < 2; ++it) {
      int e = it * 256 + tid;
      int r = e >> 2, c4 = (e & 3) * 4;
      int m = bm * 128 + r;
      float4 v = make_float4(0.f, 0.f, 0.f, 0.f);
      if (m < M) v = *(const float4*)&A[(long)m * lda + k0 + c4];
      As[c4 + 0][r] = v.x; As[c4 + 1][r] = v.y; As[c4 + 2][r] = v.z; As[c4 + 3][r] = v.w;
      int n = bn * 128 + r;
      float4 w = *(const float4*)&W[(long)n * ldw + k0 + c4];
      Bs[c4 + 0][r] = w.x; Bs[c4 + 1][r] = w.y; Bs[c4 + 2][r] = w.z; Bs[c4 + 3][r] = w.w;
    }
    __syncthreads();
#pragma unroll
    for (int kk = 0; kk < 16; ++kk) {
      float4 a0 = *(const float4*)&As[kk][tm * 8];
      float4 a1 = *(const float4*)&As[kk][tm * 8 + 4];
      float4 b0 = *(const float4*)&Bs[kk][tn * 8];
      float4 b1 = *(const float4*)&Bs[kk][tn * 8 + 4];
      float av[8] = {a0.x, a0.y, a0.z, a0.w, a1.x, a1.y, a1.z, a1.w};
      float bv[8] = {b0.x, b0.y, b0.z, b0.w, b1.x, b1.y, b1.z, b1.w};
#pragma unroll
      for (int i = 0; i < 8; ++i)
#pragma unroll
        for (int j = 0; j < 8; ++j)
          acc[i][j] += av[i] * bv[j];
    }
    __syncthreads();
  }
#pragma unroll
  for (int i = 0; i < 8; ++i) {
    int m = bm * 128 + tm * 8 + i;
    if (m >= M) continue;
#pragma unroll
    for (int j = 0; j < 8; ++j) {
      int n = bn * 128 + tn * 8 + j;
      float v = acc[i][j] + bias[n];
      if (act == 1) v = tanhf(v);
      else if (act == 2) v = log1pf(__expf(v));
      C[(long)m * ldc + n] = v;
      if (Cb) Cb[(long)m * ldc + n] = f2bf(v);
    }
  }
}

__global__ void zcalc_kernel(const float* __restrict__ zm, const float* __restrict__ zs,
                             const float* __restrict__ eps, float* __restrict__ z) {
  int e = blockIdx.x * 256 + threadIdx.x;
  if (e < BB * NZ) z[e] = zm[e] + eps[e] * zs[e];
}

__global__ void softmax_kernel(float* __restrict__ out) {
  long row = blockIdx.x;
  float* p = out + row * INPW;
  int lane = threadIdx.x;
  float v0 = (lane < INPW) ? p[lane] : -1e30f;
  float v1 = (lane + 64 < INPW) ? p[lane + 64] : -1e30f;
  float m = fmaxf(v0, v1);
#pragma unroll
  for (int off = 32; off > 0; off >>= 1) m = fmaxf(m, __shfl_xor(m, off));
  float e0 = (lane < INPW) ? __expf(v0 - m) : 0.0f;
  float e1 = (lane + 64 < INPW) ? __expf(v1 - m) : 0.0f;
  float sum = e0 + e1;
#pragma unroll
  for (int off = 32; off > 0; off >>= 1) sum += __shfl_xor(sum, off);
  float inv = 1.0f / sum;
  if (lane < INPW) p[lane] = e0 * inv;
  if (lane + 64 < INPW) p[lane + 64] = e1 * inv;
}

// ---------------- persistent encoder: LDS weights, 8 waves, dirs sequential ----------------
struct EncArgs {
  const u16* whh[2];
  const u16* xp[2];     // transposed layout [t][jb][batch][jj*4+g]
  const float* bhh[2];
  float* cst[2];
  u16* y0b;
  u16* h1a[2];
  float* htb;
  unsigned* bar;
  int layer;
};

__global__ __launch_bounds__(512) void enc_coop(EncArgs A) {
  __shared__ u16 Wl[2 * 64 * 64 * 8];               // 128 KiB
  __shared__ __align__(16) float red[4 * 64 * 4];   // 4 KiB
  const int tid = threadIdx.x;
  const int w = tid >> 6, l = tid & 63;
  const int rt = w & 1, bh = (w >> 1) & 1, kh = w >> 2;
  const int kg = l >> 4, b0 = l & 15;
  const int j0 = blockIdx.x * 8;
  const int jout = j0 + rt * 4 + kg;
  const int batch = bh * 16 + b0;
  float* redp = &red[((bh * 2 + rt) * 64 + l) * 4];

  for (int dir = 0; dir < 2; ++dir) {
    __syncthreads();
    {
      const u16* W = A.whh[dir];
      for (int e = tid; e < 8192; e += 512) {
        int ert = e >> 12, es = (e >> 6) & 63, el = e & 63;
        int etr = el & 15;
        long gr = (long)(etr & 3) * 2048 + j0 + ert * 4 + (etr >> 2);
        *(uint4*)&Wl[((ert * 64 + es) * 64 + el) * 8] =
            *(const uint4*)&W[gr * 2048 + (el >> 4) * 8 + (long)es * 32];
      }
    }
    __syncthreads();
    const float* bhh = A.bhh[dir];
    float* cst = A.cst[dir];
    const u16* xp = A.xp[dir];
    const float bi0 = bhh[jout], bi1 = bhh[2048 + jout],
                bi2 = bhh[4096 + jout], bi3 = bhh[6144 + jout];
    for (int s = 0; s < 64; ++s) {
      if (s) gbar(A.bar + (long)(dir * 63 + (s - 1)) * BSTRIDE, 32);
      const int tt = dir ? 63 - s : s;
      float xg0 = 0.f, xg1 = 0.f, xg2 = 0.f, xg3 = 0.f, co = 0.f;
      if (kh == 0) {
        const u16* xq = xp + ((((long)tt * 256 + blockIdx.x) * 32 + batch) * 32) + (rt * 4 + kg) * 4;
        ushort4 xv4 = *(const ushort4*)xq;
        xg0 = bf2f(xv4.x); xg1 = bf2f(xv4.y); xg2 = bf2f(xv4.z); xg3 = bf2f(xv4.w);
        if (s) co = cst[batch * 2048 + jout];
      }
      f32x4 acc = {0.f, 0.f, 0.f, 0.f};
      if (s) {
        const u16* hb; long hld;
        if (A.layer == 0) {
          int tp = dir ? tt + 1 : tt - 1;
          hb = A.y0b + (long)tp * 32 * 4096 + dir * 2048;
          hld = 4096;
        } else {
          hb = A.h1a[dir] + (long)(s - 1) * 32 * 2048;
          hld = 2048;
        }
        const u16* xv = hb + (long)batch * hld + kg * 8;
        for (int ks = kh * 32; ks < kh * 32 + 32; ks += 8) {
          uint4 bv[8]; short8 av[8];
#pragma unroll
          for (int uu = 0; uu < 8; ++uu)
            bv[uu] = *(const uint4*)(xv + (long)(ks + uu) * 32);
#pragma unroll
          for (int uu = 0; uu < 8; ++uu)
            av[uu] = *(const short8*)&Wl[((rt * 64 + ks + uu) * 64 + l) * 8];
#pragma unroll
          for (int uu = 0; uu < 8; ++uu)
            acc = __builtin_amdgcn_mfma_f32_16x16x32_bf16(av[uu], *(short8*)&bv[uu], acc, 0, 0, 0);
        }
      }
      __syncthreads();
      if (kh) *(f32x4*)redp = acc;
      __syncthreads();
      if (kh == 0) {
        f32x4 o = *(f32x4*)redp;
        float g0 = acc[0] + o[0] + bi0 + xg0;
        float g1 = acc[1] + o[1] + bi1 + xg1;
        float g2 = acc[2] + o[2] + bi2 + xg2;
        float g3 = acc[3] + o[3] + bi3 + xg3;
        float iv = sigf(g0), fv = sigf(g1), gv = tanhf(g2), ov = sigf(g3);
        float c = fv * co + iv * gv;
        float h = ov * tanhf(c);
        cst[batch * 2048 + jout] = c;
        if (A.layer == 0) {
          cstore2(&A.y0b[((long)tt * 32 + batch) * 4096 + dir * 2048 + jout], f2bf(h));
        } else {
          cstore2(&A.h1a[dir][((long)s * 32 + batch) * 2048 + jout], f2bf(h));
          if (s == 63) A.htb[batch * 4096 + dir * 2048 + jout] = h;
        }
      }
    }
  }
}

// ---------------- H=1024 cell, LDS weights, 8 waves (kh 4-way) ----------------
__device__ __forceinline__ void stage_w1024(u16* Wl, int m, const u16* W, int j0, int tid) {
  for (int e = tid; e < 2048; e += 512) {
    int kh = e >> 10, s = (e >> 6) & 15, el = e & 63;
    int tr = el & 15;
    long gr = (long)(tr & 3) * 1024 + j0 + (tr >> 2);
    *(uint4*)&Wl[(((m * 2 + kh) * 16 + s) * 64 + el) * 8] =
        *(const uint4*)&W[gr * 1024 + kh * 512 + (el >> 4) * 8 + s * 32];
  }
}

__device__ __forceinline__ void cell1024_lds(
    const u16* Wl, int m0, int m1,
    int j0, int tid, float* red,
    const u16* X0, long x0ld,
    const u16* X1, long x1ld,
    const u16* XQ,                       // pre-offset, layout [batch][kg*4+g], or nullptr
    const float* biasA, const float* biasB,
    const float* cin, long cld, float* cout,
    u16* hout, long hld, float* houtf, long hfld) {
  const int w = tid >> 6, l = tid & 63;
  const int bh = w & 1, kh = w >> 1;   // kh 0..3
  const int kg = l >> 4;
  const int koff = kh * 256 + kg * 8;
  const int batch = bh * 16 + (l & 15);
  const int sbase = (kh >> 1) * 16 + (kh & 1) * 8;
  const int jout = j0 + kg;
  float xg0 = 0.f, xg1 = 0.f, xg2 = 0.f, xg3 = 0.f, co = 0.f;
  float b0 = 0.f, b1 = 0.f, b2 = 0.f, b3 = 0.f;
  if (kh == 0) {
    if (XQ) {
      ushort4 v = *(const ushort4*)(XQ + (long)batch * 16 + kg * 4);
      xg0 = bf2f(v.x); xg1 = bf2f(v.y); xg2 = bf2f(v.z); xg3 = bf2f(v.w);
    }
    if (cin) co = cin[(long)batch * cld + jout];
    b0 = biasA[jout]; b1 = biasA[1024 + jout];
    b2 = biasA[2048 + jout]; b3 = biasA[3072 + jout];
    if (biasB) {
      b0 += biasB[jout]; b1 += biasB[1024 + jout];
      b2 += biasB[2048 + jout]; b3 += biasB[3072 + jout];
    }
  }
  f32x4 acc = {0.f, 0.f, 0.f, 0.f};
  if (X0) {
    const u16* xpt = X0 + (long)batch * x0ld + koff;
    const int sb = m0 * 32 + sbase;
    uint4 bv[8]; short8 av[8];
#pragma unroll
    for (int uu = 0; uu < 8; ++uu) bv[uu] = *(const uint4*)(xpt + (long)uu * 32);
#pragma unroll
    for (int uu = 0; uu < 8; ++uu) av[uu] = *(const short8*)&Wl[((sb + uu) * 64 + l) * 8];
#pragma unroll
    for (int uu = 0; uu < 8; ++uu)
      acc = __builtin_amdgcn_mfma_f32_16x16x32_bf16(av[uu], *(short8*)&bv[uu], acc, 0, 0, 0);
  }
  if (X1) {
    const u16* xpt = X1 + (long)batch * x1ld + koff;
    const int sb = m1 * 32 + sbase;
    uint4 bv[8]; short8 av[8];
#pragma unroll
    for (int uu = 0; uu < 8; ++uu) bv[uu] = *(const uint4*)(xpt + (long)uu * 32);
#pragma unroll
    for (int uu = 0; uu < 8; ++uu) av[uu] = *(const short8*)&Wl[((sb + uu) * 64 + l) * 8];
#pragma unroll
    for (int uu = 0; uu < 8; ++uu)
      acc = __builtin_amdgcn_mfma_f32_16x16x32_bf16(av[uu], *(short8*)&bv[uu], acc, 0, 0, 0);
  }
  __syncthreads();
  if (kh) *(f32x4*)&red[((kh - 1) * 2 + bh) * 256 + l * 4] = acc;
  __syncthreads();
  if (kh == 0) {
#pragma unroll
    for (int p = 0; p < 3; ++p) {
      f32x4 o = *(f32x4*)&red[(p * 2 + bh) * 256 + l * 4];
      acc[0] += o[0]; acc[1] += o[1]; acc[2] += o[2]; acc[3] += o[3];
    }
    float g0 = acc[0] + b0 + xg0;
    float g1 = acc[1] + b1 + xg1;
    float g2 = acc[2] + b2 + xg2;
    float g3 = acc[3] + b3 + xg3;
    float iv = sigf(g0), fv = sigf(g1), gv = tanhf(g2), ov = sigf(g3);
    float c = fv * co + iv * gv;
    float h = ov * tanhf(c);
    cout[(long)batch * 1024 + jout] = c;
    cstore2(&hout[(long)batch * hld + jout], f2bf(h));
    if (houtf) houtf[(long)batch * hfld + jout] = h;
  }
}

// ---------------- persistent conductor ----------------
struct CondArgs {
  const u16 *c0h, *c1w, *c1h, *tvecb;
  const float* tvec;
  u16 *yc0b, *embb;
  float* embf;
  float *cc0, *cc1;
  const float *b0i, *b0h, *b1i, *b1h;
  unsigned* bar;
};
__global__ __launch_bounds__(512) void cond_coop(CondArgs A) {
  __shared__ u16 Wl[3 * 32 * 512];                 // 96 KiB
  __shared__ __align__(16) float red[6 * 256];     // 6 KiB
  const int j0 = blockIdx.x * 4;
  const int tid = threadIdx.x;
  stage_w1024(Wl, 0, A.c0h, j0, tid);
  stage_w1024(Wl, 1, A.c1w, j0, tid);
  stage_w1024(Wl, 2, A.c1h, j0, tid);
  __syncthreads();
  int bi = 0;
  for (int u = 0; u < NU; ++u) {
    cell1024_lds(Wl, 0, -1, j0, tid, red,
                 u ? A.yc0b + (long)(u - 1) * 32 * 1024 : A.tvecb, u ? 1024 : 4096,
                 nullptr, 0,
                 nullptr,
                 A.b0i, A.b0h,
                 u ? A.cc0 : A.tvec + 2048, u ? 1024 : 4096, A.cc0,
                 A.yc0b + (long)u * 32 * 1024, 1024, nullptr, 0);
    gbar(A.bar + (long)(bi++) * BSTRIDE, 32);
    cell1024_lds(Wl, 1, 2, j0, tid, red,
                 A.yc0b + (long)u * 32 * 1024, 1024,
                 u ? A.embb + (long)(u - 1) * 32 * 1024 : A.tvecb + 1024, u ? 1024 : 4096,
                 nullptr,
                 A.b1i, A.b1h,
                 u ? A.cc1 : A.tvec + 3072, u ? 1024 : 4096, A.cc1,
                 A.embb + (long)u * 32 * 1024, 1024, A.embf + (long)u * 32 * 1024, 1024);
    if (u < NU - 1) gbar(A.bar + (long)(bi++) * BSTRIDE, 32);
  }
}

// ---------------- persistent hierarchical decoder ----------------
struct DecArgs {
  const u16 *d1h, *wfuse, *d2w, *d2h, *xeb, *sallb;
  const float* sall;
  u16 *dh1all, *dh2all;
  float *dc1, *dc2;
  const float *bfuse, *b1h, *b2i, *b2h;
  unsigned* bar;
};
__global__ __launch_bounds__(512) void dec_coop(DecArgs A) {
  __shared__ u16 Wl[4 * 32 * 512];                 // 128 KiB
  __shared__ __align__(16) float red[6 * 256];     // 6 KiB
  const int j0 = blockIdx.x * 4;
  const int tid = threadIdx.x;
  stage_w1024(Wl, 0, A.d1h, j0, tid);
  stage_w1024(Wl, 1, A.wfuse, j0, tid);
  stage_w1024(Wl, 2, A.d2w, j0, tid);
  stage_w1024(Wl, 3, A.d2h, j0, tid);
  __syncthreads();
  const u16* xqb = A.xeb + (long)blockIdx.x * 128 * 16;
  int bi = 0;
  for (int t = 0; t < TT; ++t) {
    const int u = t >> 4, sg = t & 15;
    cell1024_lds(Wl, 0, 1, j0, tid, red,
                 sg ? A.dh1all + (long)(t - 1) * 32 * 1024 : A.sallb + (long)u * 32 * 4096,
                 sg ? 1024 : 4096,
                 t ? A.dh2all + (long)(t - 1) * 32 * 1024 : nullptr, 1024,
                 xqb + (long)u * 32 * 16,
                 A.b1h, t ? A.bfuse : nullptr,
                 sg ? A.dc1 : A.sall + (long)u * 32 * 4096 + 2048, sg ? 1024 : 4096, A.dc1,
                 A.dh1all + (long)t * 32 * 1024, 1024, nullptr, 0);
    gbar(A.bar + (long)(bi++) * BSTRIDE, 32);
    cell1024_lds(Wl, 2, 3, j0, tid, red,
                 A.dh1all + (long)t * 32 * 1024, 1024,
                 sg ? A.dh2all + (long)(t - 1) * 32 * 1024 : A.sallb + (long)u * 32 * 4096 + 1024,
                 sg ? 1024 : 4096,
                 nullptr,
                 A.b2i, A.b2h,
                 sg ? A.dc2 : A.sall + (long)u * 32 * 4096 + 3072, sg ? 1024 : 4096, A.dc2,
                 A.dh2all + (long)t * 32 * 1024, 1024, nullptr, 0);
    if (t < TT - 1) gbar(A.bar + (long)(bi++) * BSTRIDE, 32);
  }
}

// ---------------- final p = dh2all @ w4^T + b4 -> out ----------------
__global__ __launch_bounds__(256) void proj_all(const u16* __restrict__ dh2all,
                                                const u16* __restrict__ w4b,
                                                const float* __restrict__ b4,
                                                float* __restrict__ out) {
  __shared__ u16 hs[8 * 1024];
  const int r0 = blockIdx.x * 8;
  for (int e = threadIdx.x; e < 1024; e += 256)
    ((uint4*)hs)[e] = ((const uint4*)(dh2all + (long)r0 * 1024))[e];
  __syncthreads();
  for (int o = threadIdx.x; o < 8 * INPW; o += 256) {
    int rr = o / INPW, n = o % INPW;
    const u16* wr = w4b + (long)n * 1024;
    const u16* hr = hs + rr * 1024;
    float s = 0.0f;
    for (int k = 0; k < 1024; ++k) s += bf2f(hr[k]) * bf2f(wr[k]);
    int row = r0 + rr;
    int tt = row >> 5, b = row & 31;
    out[((long)b * TT + tt) * INPW + n] = s + b4[n];
  }
}

// =====================================================================
extern "C" void kernel_launch(void* const* d_in, const int* in_sizes, int n_in,
                              void* d_out, int out_size, void* d_ws, size_t ws_size,
                              hipStream_t stream) {
  (void)in_sizes; (void)n_in; (void)out_size;
  const float* x        = (const float*)d_in[0];
  const float* eps      = (const float*)d_in[1];
  const float* e0f_wih  = (const float*)d_in[2];
  const float* e0f_whh  = (const float*)d_in[3];
  const float* e0f_bih  = (const float*)d_in[4];
  const float* e0f_bhh  = (const float*)d_in[5];
  const float* e0b_wih  = (const float*)d_in[6];
  const float* e0b_whh  = (const float*)d_in[7];
  const float* e0b_bih  = (const float*)d_in[8];
  const float* e0b_bhh  = (const float*)d_in[9];
  const float* e1f_wih  = (const float*)d_in[10];
  const float* e1f_whh  = (const float*)d_in[11];
  const float* e1f_bih  = (const float*)d_in[12];
  const float* e1f_bhh  = (const float*)d_in[13];
  const float* e1b_wih  = (const float*)d_in[14];
  const float* e1b_whh  = (const float*)d_in[15];
  const float* e1b_bih  = (const float*)d_in[16];
  const float* e1b_bhh  = (const float*)d_in[17];
  const float* wm  = (const float*)d_in[18];
  const float* bm  = (const float*)d_in[19];
  const float* wsw = (const float*)d_in[20];
  const float* bsv = (const float*)d_in[21];
  const float* w2  = (const float*)d_in[22];
  const float* b2  = (const float*)d_in[23];
  const float* c0_whh = (const float*)d_in[25];
  const float* c0_bih = (const float*)d_in[26];
  const float* c0_bhh = (const float*)d_in[27];
  const float* c1_wih = (const float*)d_in[28];
  const float* c1_whh = (const float*)d_in[29];
  const float* c1_bih = (const float*)d_in[30];
  const float* c1_bhh = (const float*)d_in[31];
  const float* w3 = (const float*)d_in[32];
  const float* b3 = (const float*)d_in[33];
  const float* d1_wih = (const float*)d_in[34];
  const float* d1_whh = (const float*)d_in[35];
  const float* d1_bih = (const float*)d_in[36];
  const float* d1_bhh = (const float*)d_in[37];
  const float* d2_wih = (const float*)d_in[38];
  const float* d2_whh = (const float*)d_in[39];
  const float* d2_bih = (const float*)d_in[40];
  const float* d2_bhh = (const float*)d_in[41];
  const float* w4 = (const float*)d_in[42];
  const float* b4 = (const float*)d_in[43];

  float* out = (float*)d_out;
  float* zm_out = out + (size_t)BB * TT * INPW;
  float* zs_out = zm_out + BB * NZ;

  char* wbase = (char*)d_ws;
  size_t cur = 0;
  auto AL = [&](size_t bytes) -> void* {
    void* p = wbase + cur;
    cur = (cur + bytes + 255) & ~(size_t)255;
    return p;
  };
  u16* xb    = (u16*)AL(2048L * 128 * 2);
  u16* e0wf  = (u16*)AL(8192L * 128 * 2);
  u16* e0wb  = (u16*)AL(8192L * 128 * 2);
  u16* e0hf  = (u16*)AL(8192L * 2048 * 2);
  u16* e0hb  = (u16*)AL(8192L * 2048 * 2);
  u16* e1wf  = (u16*)AL(8192L * 4096 * 2);
  u16* e1wb  = (u16*)AL(8192L * 4096 * 2);
  u16* e1hf  = (u16*)AL(8192L * 2048 * 2);
  u16* e1hb  = (u16*)AL(8192L * 2048 * 2);
  u16* c0h   = (u16*)AL(4096L * 1024 * 2);
  u16* c1w   = (u16*)AL(4096L * 1024 * 2);
  u16* c1h   = (u16*)AL(4096L * 1024 * 2);
  u16* d1we  = (u16*)AL(4096L * 1024 * 2);
  u16* d1wp  = (u16*)AL(4096L * 128 * 2);
  u16* d1h   = (u16*)AL(4096L * 1024 * 2);
  u16* d2w   = (u16*)AL(4096L * 1024 * 2);
  u16* d2h   = (u16*)AL(4096L * 1024 * 2);
  u16* w4b   = (u16*)AL(90L * 1024 * 2);
  u16* w4tb  = (u16*)AL(1024L * 128 * 2);
  u16* wfuse = (u16*)AL(4096L * 1024 * 2);
  float* bfuse = (float*)AL(4096L * 4);
  u16* xp0f  = (u16*)AL(2048L * 8192 * 2);
  u16* xp0b  = (u16*)AL(2048L * 8192 * 2);
  u16* y0b   = (u16*)AL(2048L * 4096 * 2);
  u16* xp1f  = (u16*)AL(2048L * 8192 * 2);
  u16* xp1b  = (u16*)AL(2048L * 8192 * 2);
  u16* h1af  = (u16*)AL(64L * 32 * 2048 * 2);
  u16* h1ab  = (u16*)AL(64L * 32 * 2048 * 2);
  u16* tvecb = (u16*)AL(32L * 4096 * 2);
  u16* yc0b  = (u16*)AL(4L * 32 * 1024 * 2);
  u16* embb  = (u16*)AL(4L * 32 * 1024 * 2);
  u16* sallb = (u16*)AL(128L * 4096 * 2);
  u16* xeb   = (u16*)AL(128L * 4096 * 2);
  u16* dh1all= (u16*)AL(64L * 32 * 1024 * 2);
  u16* dh2all= (u16*)AL(64L * 32 * 1024 * 2);
  float* c0f_ = (float*)AL(32L * 2048 * 4);
  float* c0b_ = (float*)AL(32L * 2048 * 4);
  float* c1f_ = (float*)AL(32L * 2048 * 4);
  float* c1b_ = (float*)AL(32L * 2048 * 4);
  float* htb  = (float*)AL(32L * 4096 * 4);
  float* zbuf = (float*)AL(32L * 512 * 4);
  float* tvec = (float*)AL(32L * 4096 * 4);
  float* cc0  = (float*)AL(32L * 1024 * 4);
  float* cc1  = (float*)AL(32L * 1024 * 4);
  float* embf = (float*)AL(128L * 1024 * 4);
  float* sall = (float*)AL(128L * 4096 * 4);
  float* dc1  = (float*)AL(32L * 1024 * 4);
  float* dc2  = (float*)AL(32L * 1024 * 4);
  unsigned* barp = (unsigned*)AL(400L * BSTRIDE * 4);
  if (cur > ws_size) return;

  unsigned* bar_enc0 = barp;
  unsigned* bar_enc1 = barp + 128L * BSTRIDE;
  unsigned* bar_cond = barp + 256L * BSTRIDE;
  unsigned* bar_dec  = barp + 264L * BSTRIDE;

  // ---- conversions ----
  auto cf = [&](const float* s, u16* d, long n) {
    cvt_flat<<<dim3((unsigned)((n / 4 + 255) / 256)), 256, 0, stream>>>(s, d, n);
  };
  cf(e0f_whh, e0hf, 8192L * 2048);
  cf(e0b_whh, e0hb, 8192L * 2048);
  cf(e1f_wih, e1wf, 8192L * 4096);
  cf(e1b_wih, e1wb, 8192L * 4096);
  cf(e1f_whh, e1hf, 8192L * 2048);
  cf(e1b_whh, e1hb, 8192L * 2048);
  cf(c0_whh, c0h, 4096L * 1024);
  cf(c1_wih, c1w, 4096L * 1024);
  cf(c1_whh, c1h, 4096L * 1024);
  cf(d1_whh, d1h, 4096L * 1024);
  cf(d2_wih, d2w, 4096L * 1024);
  cf(d2_whh, d2h, 4096L * 1024);
  cf(w4, w4b, 90L * 1024);
  cvt_pad<<<dim3(1, 8192), 128, 0, stream>>>(e0f_wih, 90, 90, e0wf, 128, 8192);
  cvt_pad<<<dim3(1, 8192), 128, 0, stream>>>(e0b_wih, 90, 90, e0wb, 128, 8192);
  cvt_pad<<<dim3(4, 4096), 256, 0, stream>>>(d1_wih, 1114, 1024, d1we, 1024, 4096);
  cvt_pad<<<dim3(1, 4096), 128, 0, stream>>>(d1_wih + 1024, 1114, 90, d1wp, 128, 4096);
  xcvt<<<dim3(2048), 128, 0, stream>>>(x, xb);
  w4t_k<<<dim3(1024), 128, 0, stream>>>(w4, w4tb);
  bfuse_k<<<dim3(16), 256, 0, stream>>>(d1_wih, b4, bfuse);
  hipMemsetAsync(barp, 0, 400L * BSTRIDE * 4, stream);

  gemm_bf<<<dim3(32, 8), 256, 0, stream>>>(d1wp, 128, w4tb, 128, nullptr, wfuse, 1024, 128, 0);
  gemm_bf<<<dim3(16, 64), 256, 0, stream>>>(xb, 128, e0wf, 128, e0f_bih, xp0f, 8192, 128, 1);
  gemm_bf<<<dim3(16, 64), 256, 0, stream>>>(xb, 128, e0wb, 128, e0b_bih, xp0b, 8192, 128, 1);

  // ---- encoder layer 0 ----
  {
    EncArgs ea{};
    ea.whh[0] = e0hf; ea.whh[1] = e0hb;
    ea.xp[0] = xp0f; ea.xp[1] = xp0b;
    ea.bhh[0] = e0f_bhh; ea.bhh[1] = e0b_bhh;
    ea.cst[0] = c0f_; ea.cst[1] = c0b_;
    ea.y0b = y0b; ea.h1a[0] = h1af; ea.h1a[1] = h1ab; ea.htb = htb;
    ea.bar = bar_enc0; ea.layer = 0;
    void* args[] = {&ea};
    hipLaunchCooperativeKernel((void*)enc_coop, dim3(256), dim3(512), args, 0, stream);
  }

  gemm_bf<<<dim3(16, 64), 256, 0, stream>>>(y0b, 4096, e1wf, 4096, e1f_bih, xp1f, 8192, 4096, 1);
  gemm_bf<<<dim3(16, 64), 256, 0, stream>>>(y0b, 4096, e1wb, 4096, e1b_bih, xp1b, 8192, 4096, 1);

  // ---- encoder layer 1 ----
  {
    EncArgs ea{};
    ea.whh[0] = e1hf; ea.whh[1] = e1hb;
    ea.xp[0] = xp1f; ea.xp[1] = xp1b;
    ea.bhh[0] = e1f_bhh; ea.bhh[1] = e1b_bhh;
    ea.cst[0] = c1f_; ea.cst[1] = c1b_;
    ea.y0b = y0b; ea.h1a[0] = h1af; ea.h1a[1] = h1ab; ea.htb = htb;
    ea.bar = bar_enc1; ea.layer = 1;
    void* args[] = {&ea};
    hipLaunchCooperativeKernel((void*)enc_coop, dim3(256), dim3(512), args, 0, stream);
  }

  // ---- latent ----
  gemm128<<<dim3(1, 4), 256, 0, stream>>>(htb, 4096, wm, 4096, bm, zm_out, 512, 32, 4096, 0, nullptr);
  gemm128<<<dim3(1, 4), 256, 0, stream>>>(htb, 4096, wsw, 4096, bsv, zs_out, 512, 32, 4096, 2, nullptr);
  zcalc_kernel<<<dim3(64), 256, 0, stream>>>(zm_out, zs_out, eps, zbuf);
  gemm128<<<dim3(1, 32), 256, 0, stream>>>(zbuf, 512, w2, 512, b2, tvec, 4096, 32, 512, 1, tvecb);

  // ---- conductor ----
  {
    CondArgs ca{};
    ca.c0h = c0h; ca.c1w = c1w; ca.c1h = c1h;
    ca.tvecb = tvecb; ca.tvec = tvec;
    ca.yc0b = yc0b; ca.embb = embb; ca.embf = embf;
    ca.cc0 = cc0; ca.cc1 = cc1;
    ca.b0i = c0_bih; ca.b0h = c0_bhh; ca.b1i = c1_bih; ca.b1h = c1_bhh;
    ca.bar = bar_cond;
    void* args[] = {&ca};
    hipLaunchCooperativeKernel((void*)cond_coop, dim3(256), dim3(512), args, 0, stream);
  }

  // ---- decoder prep ----
  gemm128<<<dim3(1, 32), 256, 0, stream>>>(embf, 1024, w3, 1024, b3, sall, 4096, 128, 1024, 1, sallb);
  gemm_bf<<<dim3(1, 32), 256, 0, stream>>>(embb, 1024, d1we, 1024, d1_bih, xeb, 4096, 1024, 2);

  // ---- hierarchical decoder ----
  {
    DecArgs da{};
    da.d1h = d1h; da.wfuse = wfuse; da.d2w = d2w; da.d2h = d2h;
    da.xeb = xeb; da.sallb = sallb; da.sall = sall;
    da.dh1all = dh1all; da.dh2all = dh2all;
    da.dc1 = dc1; da.dc2 = dc2;
    da.bfuse = bfuse; da.b1h = d1_bhh; da.b2i = d2_bih; da.b2h = d2_bhh;
    da.bar = bar_dec;
    void* args[] = {&da};
    hipLaunchCooperativeKernel((void*)dec_coop, dim3(256), dim3(512), args, 0, stream);
  }

  // ---- outputs ----
  proj_all<<<dim3(256), 256, 0, stream>>>(dh2all, w4b, b4, out);
  softmax_kernel<<<dim3(BB * TT), 64, 0, stream>>>(out);
}